// Round 1
// baseline (3787.269 us; speedup 1.0000x reference)
//
#include <hip/hip_runtime.h>
#include <math.h>
#include <float.h>

// Problem constants (from reference)
#define NB 2
#define LQ 2048
#define HH 8
#define EE 64
#define SS 2048
#define CC 256
#define KM_ITERS 10
#define NBITS 32
#define TK 32
#define NH (NB*HH)

// ---------------- K1: hash bits -> 32-bit mask per (n,h,l) ----------------
__global__ __launch_bounds__(256) void k_hash(const float* __restrict__ Q,
                                              const float* __restrict__ planes,
                                              unsigned int* __restrict__ qmask) {
    int gid = blockIdx.x * 256 + threadIdx.x;      // nh*LQ + l
    int nh = gid >> 11, l = gid & (LQ - 1);
    int n = nh >> 3, h = nh & 7;
    const float* qrow = Q + (((size_t)n * LQ + l) * HH + h) * EE;
    float q[64];
    #pragma unroll
    for (int e = 0; e < 64; e++) q[e] = qrow[e];
    unsigned int m = 0;
    for (int b = 0; b < NBITS; b++) {
        double acc = (double)planes[b * 65 + 64];   // bias
        #pragma unroll
        for (int e = 0; e < 64; e++) acc += (double)q[e] * (double)planes[b * 65 + e];
        if (acc > 0.0) m |= (1u << b);
    }
    qmask[gid] = m;
}

// ---------------- K2: k-means in Hamming space, exact integer ----------------
__global__ __launch_bounds__(256) void k_kmeans(const unsigned int* __restrict__ qmask,
                                                int* __restrict__ clusters,
                                                int* __restrict__ counts_out) {
    int nh = blockIdx.x;
    int t = threadIdx.x;
    __shared__ unsigned int cent[CC];
    __shared__ unsigned int qm[LQ];         // 8KB
    __shared__ unsigned short asg[LQ];      // 4KB
    const unsigned int* qb = qmask + (size_t)nh * LQ;
    for (int j = 0; j < LQ / 256; j++) qm[t + j * 256] = qb[t + j * 256];
    cent[t] = qb[t * 8];                    // init_idx = c * (2048/256) = c*8
    __syncthreads();
    unsigned int mym[8];
    #pragma unroll
    for (int j = 0; j < 8; j++) mym[j] = qm[t + j * 256];

    for (int it = 0; it < KM_ITERS; ++it) {
        // assign: strict '<' ascending c = first-min tie break (matches jnp.argmin)
        int bd[8], bc[8];
        #pragma unroll
        for (int j = 0; j < 8; j++) { bd[j] = 1000; bc[j] = 0; }
        for (int c = 0; c < CC; c++) {
            unsigned int cm = cent[c];
            #pragma unroll
            for (int j = 0; j < 8; j++) {
                int d = __popc(mym[j] ^ cm);
                if (d < bd[j]) { bd[j] = d; bc[j] = c; }
            }
        }
        #pragma unroll
        for (int j = 0; j < 8; j++) asg[t + j * 256] = (unsigned short)bc[j];
        __syncthreads();
        // update: thread t owns cluster t; exact integer majority test 2*sum >= count
        int cnt = 0; int bs[32];
        #pragma unroll
        for (int b = 0; b < 32; b++) bs[b] = 0;
        for (int p = 0; p < LQ; p++) {
            if (asg[p] == (unsigned short)t) {
                unsigned int m = qm[p]; cnt++;
                #pragma unroll
                for (int b = 0; b < 32; b++) bs[b] += (m >> b) & 1;
            }
        }
        if (cnt > 0) {
            unsigned int nc = 0;
            #pragma unroll
            for (int b = 0; b < 32; b++) if (2 * bs[b] >= cnt) nc |= (1u << b);
            cent[t] = nc;
        }
        __syncthreads();
    }
    // final assign
    for (int j = 0; j < 8; j++) {
        unsigned int m = mym[j];
        int bd = 1000, bc = 0;
        for (int c = 0; c < CC; c++) {
            int d = __popc(m ^ cent[c]);
            if (d < bd) { bd = d; bc = c; }
        }
        asg[t + j * 256] = (unsigned short)bc;
        clusters[(size_t)nh * LQ + t + j * 256] = bc;
    }
    __syncthreads();
    int cnt = 0;
    for (int p = 0; p < LQ; p++) if (asg[p] == (unsigned short)t) cnt++;
    counts_out[nh * CC + t] = cnt;
}

// ---------------- K3: cluster-mean queries Qg (f64) ----------------
// grid: nh*4 blocks; block (nh, e-quarter of 16 dims); thread t owns cluster t
__global__ __launch_bounds__(256) void k_qg(const float* __restrict__ Q,
                                            const int* __restrict__ clusters,
                                            const int* __restrict__ counts,
                                            double* __restrict__ Qg) {
    int nh = blockIdx.x >> 2, eq = blockIdx.x & 3, e0 = eq * 16;
    int t = threadIdx.x;
    int n = nh >> 3, h = nh & 7;
    __shared__ int cl[LQ];
    for (int j = 0; j < 8; j++) cl[t + j * 256] = clusters[(size_t)nh * LQ + t + j * 256];
    __syncthreads();
    double acc[16];
    #pragma unroll
    for (int i = 0; i < 16; i++) acc[i] = 0.0;
    for (int p = 0; p < LQ; p++) {
        if (cl[p] == t) {
            const float* qr = Q + (((size_t)n * LQ + p) * HH + h) * EE + e0;
            #pragma unroll
            for (int i = 0; i < 16; i++) acc[i] += (double)qr[i];
        }
    }
    int cnt = counts[nh * CC + t];
    double safe = cnt > 0 ? (double)cnt : 1.0;
    double* o = Qg + ((size_t)(nh * CC + t)) * EE + e0;
    #pragma unroll
    for (int i = 0; i < 16; i++) o[i] = acc[i] / safe;
}

// ---------------- K4: per-(nh,c) row: QK(f64) -> max/denom -> top32 -> Vg, A_bk ----------------
__global__ __launch_bounds__(256) void k_rows(const float* __restrict__ Kp,
                                              const float* __restrict__ Vp,
                                              const double* __restrict__ Qg,
                                              int* __restrict__ topi,
                                              float* __restrict__ abk,
                                              float* __restrict__ Vg) {
    int bid = blockIdx.x;
    int c = bid & (CC - 1), nh = bid >> 8;
    int n = nh >> 3, h = nh & 7;
    int t = threadIdx.x, wid = t >> 6, lane = t & 63;
    __shared__ double qg[64];
    __shared__ double xrow[SS];      // 16KB
    __shared__ float  wrow[SS];      // 8KB
    __shared__ double rv4[4];
    __shared__ int    ri4[4];
    __shared__ double redv[256];     // 2KB
    __shared__ int    topis[TK];

    if (t < 64) qg[t] = Qg[((size_t)(nh * CC + c)) * EE + t];
    __syncthreads();
    // QK row, f64 accumulate
    for (int j = 0; j < 8; j++) {
        int s = t + j * 256;
        const float* kr = Kp + (((size_t)n * SS + s) * HH + h) * EE;
        double acc = 0.0;
        #pragma unroll
        for (int e = 0; e < 64; e++) acc += qg[e] * (double)kr[e];
        xrow[s] = acc;
    }
    __syncthreads();
    // row max
    double lm = -1e300;
    for (int j = 0; j < 8; j++) { double v = xrow[t + j * 256]; lm = v > lm ? v : lm; }
    #pragma unroll
    for (int o = 32; o > 0; o >>= 1) { double v = __shfl_xor(lm, o); lm = v > lm ? v : lm; }
    if (lane == 0) rv4[wid] = lm;
    __syncthreads();
    double m = rv4[0];
    #pragma unroll
    for (int i = 1; i < 4; i++) { double v = rv4[i]; m = v > m ? v : m; }
    // softmax denominator over full row (before masking)
    double ls = 0.0;
    for (int j = 0; j < 8; j++) ls += exp(0.125 * (xrow[t + j * 256] - m));
    #pragma unroll
    for (int o = 32; o > 0; o >>= 1) ls += __shfl_xor(ls, o);
    __syncthreads();
    if (lane == 0) rv4[wid] = ls;
    __syncthreads();
    double denom = rv4[0] + rv4[1] + rv4[2] + rv4[3];
    __syncthreads();
    // top-32: iterated argmax, tie -> lowest index (matches lax.top_k set)
    double topsum = 0.0;
    for (int k = 0; k < TK; k++) {
        double bv = -1e301; int bi = 1 << 30;
        for (int j = 0; j < 8; j++) {
            int s = t + j * 256; double v = xrow[s];
            if (v > bv || (v == bv && s < bi)) { bv = v; bi = s; }
        }
        #pragma unroll
        for (int o = 32; o > 0; o >>= 1) {
            double v2 = __shfl_xor(bv, o); int i2 = __shfl_xor(bi, o);
            if (v2 > bv || (v2 == bv && i2 < bi)) { bv = v2; bi = i2; }
        }
        if (lane == 0) { rv4[wid] = bv; ri4[wid] = bi; }
        __syncthreads();
        if (t == 0) {
            double fv = rv4[0]; int fi = ri4[0];
            #pragma unroll
            for (int i = 1; i < 4; i++) {
                double v2 = rv4[i]; int i2 = ri4[i];
                if (v2 > fv || (v2 == fv && i2 < fi)) { fv = v2; fi = i2; }
            }
            topis[k] = fi;
            topsum += exp(0.125 * (fv - m));
            xrow[fi] = -HUGE_VAL;   // masked -> exp() = 0 later
        }
        __syncthreads();
    }
    if (t == 0) abk[nh * CC + c] = (float)((denom - topsum) / denom);
    if (t < TK) topi[(size_t)(nh * CC + c) * TK + t] = topis[t];
    // masked softmax weights
    for (int j = 0; j < 8; j++) {
        int s = t + j * 256;
        wrow[s] = (float)(exp(0.125 * (xrow[s] - m)) / denom);
    }
    __syncthreads();
    // Vg[e] = sum_s w[s] * V[s][e]
    int e = t & 63, qq = t >> 6;
    double acc = 0.0;
    const float* vbase = Vp + ((size_t)n * SS) * HH * EE + (size_t)h * EE + e;
    for (int s = qq * 512; s < qq * 512 + 512; s++) {
        acc += (double)wrow[s] * (double)vbase[(size_t)s * HH * EE];
    }
    redv[t] = acc;
    __syncthreads();
    if (t < 64)
        Vg[((size_t)(nh * CC + c)) * EE + t] =
            (float)(redv[t] + redv[t + 64] + redv[t + 128] + redv[t + 192]);
}

// ---------------- K5: per-query top-32 re-attention + V_bottom ----------------
// wave per query; lane = e dim
__global__ __launch_bounds__(256) void k_out(const float* __restrict__ Q,
                                             const float* __restrict__ Kp,
                                             const float* __restrict__ Vp,
                                             const int* __restrict__ clusters,
                                             const int* __restrict__ topi,
                                             const float* __restrict__ abk,
                                             const float* __restrict__ Vg,
                                             float* __restrict__ out) {
    int tid = threadIdx.x, wid = tid >> 6, e = tid & 63;
    int q = blockIdx.x * 4 + wid;            // nh*LQ + l
    int nh = q >> 11, l = q & (LQ - 1);
    int n = nh >> 3, h = nh & 7;
    int c = clusters[q];
    float scale = 1.0f - abk[nh * CC + c];
    const int* ti = topi + (size_t)(nh * CC + c) * TK;
    float qe = Q[(((size_t)n * LQ + l) * HH + h) * EE + e];
    float myv = -INFINITY;
    for (int k = 0; k < TK; k++) {
        int idx = ti[k];
        float kv = Kp[(((size_t)n * SS + idx) * HH + h) * EE + e];
        float v = qe * kv;
        #pragma unroll
        for (int o = 32; o > 0; o >>= 1) v += __shfl_xor(v, o);
        if (e == k) myv = v;
    }
    float mv = myv;
    #pragma unroll
    for (int o = 32; o > 0; o >>= 1) { float v = __shfl_xor(mv, o); mv = v > mv ? v : mv; }
    float p = (e < TK) ? expf(0.125f * (myv - mv)) : 0.0f;
    float ssum = p;
    #pragma unroll
    for (int o = 32; o > 0; o >>= 1) ssum += __shfl_xor(ssum, o);
    float at = p / ssum * scale;
    float acc = 0.0f;
    for (int k = 0; k < TK; k++) {
        float wk = __shfl(at, k, 64);
        int idx = ti[k];
        acc += wk * Vp[(((size_t)n * SS + idx) * HH + h) * EE + e];
    }
    acc += Vg[(size_t)(nh * CC + c) * EE + e];
    out[(((size_t)n * LQ + l) * HH + h) * EE + e] = acc;
}

extern "C" void kernel_launch(void* const* d_in, const int* in_sizes, int n_in,
                              void* d_out, int out_size, void* d_ws, size_t ws_size,
                              hipStream_t stream) {
    const float* Q      = (const float*)d_in[0];
    const float* K      = (const float*)d_in[1];
    const float* V      = (const float*)d_in[2];
    const float* planes = (const float*)d_in[3];
    float* out = (float*)d_out;

    char* ws = (char*)d_ws;
    // layout (all 8B-aligned): ~3.9MB total
    unsigned int* qmask    = (unsigned int*)(ws);                  // 128KB
    int*          clusters = (int*)(ws + (128 << 10));             // 128KB
    int*          counts   = (int*)(ws + (256 << 10));             // 16KB
    float*        abk      = (float*)(ws + (272 << 10));           // 16KB
    int*          topi     = (int*)(ws + (288 << 10));             // 512KB
    float*        Vg       = (float*)(ws + (800 << 10));           // 1MB
    double*       Qg       = (double*)(ws + (1824 << 10));         // 2MB

    k_hash<<<dim3(NH * LQ / 256), dim3(256), 0, stream>>>(Q, planes, qmask);
    k_kmeans<<<dim3(NH), dim3(256), 0, stream>>>(qmask, clusters, counts);
    k_qg<<<dim3(NH * 4), dim3(256), 0, stream>>>(Q, clusters, counts, Qg);
    k_rows<<<dim3(NH * CC), dim3(256), 0, stream>>>(K, V, Qg, topi, abk, Vg);
    k_out<<<dim3(NH * LQ / 4), dim3(256), 0, stream>>>(Q, K, V, clusters, topi, abk, Vg, out);
}

// Round 2
// 1315.796 us; speedup vs baseline: 2.8783x; 2.8783x over previous
//
#include <hip/hip_runtime.h>
#include <math.h>
#include <float.h>

// Problem constants (from reference)
#define NB 2
#define LQ 2048
#define HH 8
#define EE 64
#define SS 2048
#define CC 256
#define KM_ITERS 10
#define NBITS 32
#define TK 32
#define NH (NB*HH)

// ---------------- K1: hash bits -> 32-bit mask per (n,h,l) ----------------
__global__ __launch_bounds__(256) void k_hash(const float* __restrict__ Q,
                                              const float* __restrict__ planes,
                                              unsigned int* __restrict__ qmask) {
    int gid = blockIdx.x * 256 + threadIdx.x;      // nh*LQ + l
    int nh = gid >> 11, l = gid & (LQ - 1);
    int n = nh >> 3, h = nh & 7;
    const float* qrow = Q + (((size_t)n * LQ + l) * HH + h) * EE;
    float q[64];
    #pragma unroll
    for (int e = 0; e < 64; e++) q[e] = qrow[e];
    unsigned int m = 0;
    for (int b = 0; b < NBITS; b++) {
        double acc = (double)planes[b * 65 + 64];   // bias
        #pragma unroll
        for (int e = 0; e < 64; e++) acc += (double)q[e] * (double)planes[b * 65 + e];
        if (acc > 0.0) m |= (1u << b);
    }
    qmask[gid] = m;
}

// ---------------- K2: k-means in Hamming space, exact integer ----------------
// Counting-sort restructure: assign (uint4 centroid reads, ILP) -> counts via
// LDS atomics -> Hillis-Steele scan -> scatter -> per-cluster update scanning
// only own points (avg 8). All decisions exact-integer; sums order-independent.
__global__ __launch_bounds__(256) void k_kmeans(const unsigned int* __restrict__ qmask,
                                                int* __restrict__ clusters,
                                                int* __restrict__ counts_out) {
    int nh = blockIdx.x;
    int t = threadIdx.x;
    __shared__ __align__(16) unsigned int cent[CC];   // 1KB
    __shared__ unsigned int qm[LQ];                   // 8KB
    __shared__ unsigned int sorted[LQ];               // 8KB
    __shared__ int cnts[CC];                          // 1KB
    __shared__ int scan[CC];                          // 1KB
    __shared__ int cursor[CC];                        // 1KB
    const unsigned int* qb = qmask + (size_t)nh * LQ;
    #pragma unroll
    for (int j = 0; j < 8; j++) qm[t + j * 256] = qb[t + j * 256];
    cent[t] = qb[t * 8];                    // init_idx = c * (2048/256) = c*8
    __syncthreads();
    unsigned int mym[8];
    #pragma unroll
    for (int j = 0; j < 8; j++) mym[j] = qm[t + j * 256];

    int bc[8];
    for (int it = 0; it <= KM_ITERS; ++it) {
        // ---- assign: strict '<' ascending c = first-min (matches jnp.argmin) ----
        int bd[8];
        #pragma unroll
        for (int j = 0; j < 8; j++) { bd[j] = 1000; bc[j] = 0; }
        for (int c4 = 0; c4 < CC; c4 += 4) {
            uint4 cm = *(const uint4*)&cent[c4];
            #pragma unroll
            for (int j = 0; j < 8; j++) {
                int d0 = __popc(mym[j] ^ cm.x);
                int d1 = __popc(mym[j] ^ cm.y);
                int d2 = __popc(mym[j] ^ cm.z);
                int d3 = __popc(mym[j] ^ cm.w);
                if (d0 < bd[j]) { bd[j] = d0; bc[j] = c4; }
                if (d1 < bd[j]) { bd[j] = d1; bc[j] = c4 + 1; }
                if (d2 < bd[j]) { bd[j] = d2; bc[j] = c4 + 2; }
                if (d3 < bd[j]) { bd[j] = d3; bc[j] = c4 + 3; }
            }
        }
        if (it == KM_ITERS) break;          // 11th pass = final assign only

        // ---- counting sort ----
        cnts[t] = 0;
        __syncthreads();
        #pragma unroll
        for (int j = 0; j < 8; j++) atomicAdd(&cnts[bc[j]], 1);
        __syncthreads();
        scan[t] = cnts[t];
        __syncthreads();
        #pragma unroll
        for (int d = 1; d < CC; d <<= 1) {
            int v = scan[t];
            int add = (t >= d) ? scan[t - d] : 0;
            __syncthreads();
            scan[t] = v + add;
            __syncthreads();
        }
        int offt = scan[t] - cnts[t];       // exclusive prefix
        cursor[t] = offt;
        __syncthreads();
        #pragma unroll
        for (int j = 0; j < 8; j++) {
            int pos = atomicAdd(&cursor[bc[j]], 1);
            sorted[pos] = mym[j];
        }
        __syncthreads();

        // ---- update: thread t owns cluster t, scans only its own points ----
        int cnt = cnts[t];
        if (cnt > 0) {
            int bs[32];
            #pragma unroll
            for (int b = 0; b < 32; b++) bs[b] = 0;
            for (int i = 0; i < cnt; i++) {
                unsigned int m = sorted[offt + i];
                #pragma unroll
                for (int b = 0; b < 32; b++) bs[b] += (m >> b) & 1;
            }
            unsigned int nc = 0;
            #pragma unroll
            for (int b = 0; b < 32; b++) if (2 * bs[b] >= cnt) nc |= (1u << b);
            cent[t] = nc;                   // exact majority: 2*sum >= cnt
        }
        __syncthreads();
    }

    // ---- write final assignment + counts ----
    cnts[t] = 0;
    __syncthreads();
    #pragma unroll
    for (int j = 0; j < 8; j++) {
        clusters[(size_t)nh * LQ + t + j * 256] = bc[j];
        atomicAdd(&cnts[bc[j]], 1);
    }
    __syncthreads();
    counts_out[nh * CC + t] = cnts[t];
}

// ---------------- K3: cluster-mean queries Qg (f64) ----------------
__global__ __launch_bounds__(256) void k_qg(const float* __restrict__ Q,
                                            const int* __restrict__ clusters,
                                            const int* __restrict__ counts,
                                            double* __restrict__ Qg) {
    int nh = blockIdx.x >> 2, eq = blockIdx.x & 3, e0 = eq * 16;
    int t = threadIdx.x;
    int n = nh >> 3, h = nh & 7;
    __shared__ int cl[LQ];
    for (int j = 0; j < 8; j++) cl[t + j * 256] = clusters[(size_t)nh * LQ + t + j * 256];
    __syncthreads();
    double acc[16];
    #pragma unroll
    for (int i = 0; i < 16; i++) acc[i] = 0.0;
    for (int p = 0; p < LQ; p++) {
        if (cl[p] == t) {
            const float* qr = Q + (((size_t)n * LQ + p) * HH + h) * EE + e0;
            #pragma unroll
            for (int i = 0; i < 16; i++) acc[i] += (double)qr[i];
        }
    }
    int cnt = counts[nh * CC + t];
    double safe = cnt > 0 ? (double)cnt : 1.0;
    double* o = Qg + ((size_t)(nh * CC + t)) * EE + e0;
    #pragma unroll
    for (int i = 0; i < 16; i++) o[i] = acc[i] / safe;
}

// ---------------- K4: per-(nh,c) row: QK(f64) -> max/denom -> top32 -> Vg, A_bk ----------------
__global__ __launch_bounds__(256) void k_rows(const float* __restrict__ Kp,
                                              const float* __restrict__ Vp,
                                              const double* __restrict__ Qg,
                                              int* __restrict__ topi,
                                              float* __restrict__ abk,
                                              float* __restrict__ Vg) {
    int bid = blockIdx.x;
    int c = bid & (CC - 1), nh = bid >> 8;
    int n = nh >> 3, h = nh & 7;
    int t = threadIdx.x, wid = t >> 6, lane = t & 63;
    __shared__ double qg[64];
    __shared__ double xrow[SS];      // 16KB
    __shared__ float  wrow[SS];      // 8KB
    __shared__ double rv4[4];
    __shared__ int    ri4[4];
    __shared__ double redv[256];     // 2KB
    __shared__ int    topis[TK];

    if (t < 64) qg[t] = Qg[((size_t)(nh * CC + c)) * EE + t];
    __syncthreads();
    // QK row, f64 accumulate
    for (int j = 0; j < 8; j++) {
        int s = t + j * 256;
        const float* kr = Kp + (((size_t)n * SS + s) * HH + h) * EE;
        double acc = 0.0;
        #pragma unroll
        for (int e = 0; e < 64; e++) acc += qg[e] * (double)kr[e];
        xrow[s] = acc;
    }
    __syncthreads();
    // row max
    double lm = -1e300;
    for (int j = 0; j < 8; j++) { double v = xrow[t + j * 256]; lm = v > lm ? v : lm; }
    #pragma unroll
    for (int o = 32; o > 0; o >>= 1) { double v = __shfl_xor(lm, o); lm = v > lm ? v : lm; }
    if (lane == 0) rv4[wid] = lm;
    __syncthreads();
    double m = rv4[0];
    #pragma unroll
    for (int i = 1; i < 4; i++) { double v = rv4[i]; m = v > m ? v : m; }
    // softmax denominator over full row (before masking)
    double ls = 0.0;
    for (int j = 0; j < 8; j++) ls += exp(0.125 * (xrow[t + j * 256] - m));
    #pragma unroll
    for (int o = 32; o > 0; o >>= 1) ls += __shfl_xor(ls, o);
    __syncthreads();
    if (lane == 0) rv4[wid] = ls;
    __syncthreads();
    double denom = rv4[0] + rv4[1] + rv4[2] + rv4[3];
    __syncthreads();
    // top-32: iterated argmax, tie -> lowest index (matches lax.top_k set)
    double topsum = 0.0;
    for (int k = 0; k < TK; k++) {
        double bv = -1e301; int bi = 1 << 30;
        for (int j = 0; j < 8; j++) {
            int s = t + j * 256; double v = xrow[s];
            if (v > bv || (v == bv && s < bi)) { bv = v; bi = s; }
        }
        #pragma unroll
        for (int o = 32; o > 0; o >>= 1) {
            double v2 = __shfl_xor(bv, o); int i2 = __shfl_xor(bi, o);
            if (v2 > bv || (v2 == bv && i2 < bi)) { bv = v2; bi = i2; }
        }
        if (lane == 0) { rv4[wid] = bv; ri4[wid] = bi; }
        __syncthreads();
        if (t == 0) {
            double fv = rv4[0]; int fi = ri4[0];
            #pragma unroll
            for (int i = 1; i < 4; i++) {
                double v2 = rv4[i]; int i2 = ri4[i];
                if (v2 > fv || (v2 == fv && i2 < fi)) { fv = v2; fi = i2; }
            }
            topis[k] = fi;
            topsum += exp(0.125 * (fv - m));
            xrow[fi] = -HUGE_VAL;   // masked -> exp() = 0 later
        }
        __syncthreads();
    }
    if (t == 0) abk[nh * CC + c] = (float)((denom - topsum) / denom);
    if (t < TK) topi[(size_t)(nh * CC + c) * TK + t] = topis[t];
    // masked softmax weights
    for (int j = 0; j < 8; j++) {
        int s = t + j * 256;
        wrow[s] = (float)(exp(0.125 * (xrow[s] - m)) / denom);
    }
    __syncthreads();
    // Vg[e] = sum_s w[s] * V[s][e]
    int e = t & 63, qq = t >> 6;
    double acc = 0.0;
    const float* vbase = Vp + ((size_t)n * SS) * HH * EE + (size_t)h * EE + e;
    for (int s = qq * 512; s < qq * 512 + 512; s++) {
        acc += (double)wrow[s] * (double)vbase[(size_t)s * HH * EE];
    }
    redv[t] = acc;
    __syncthreads();
    if (t < 64)
        Vg[((size_t)(nh * CC + c)) * EE + t] =
            (float)(redv[t] + redv[t + 64] + redv[t + 128] + redv[t + 192]);
}

// ---------------- K5: per-query top-32 re-attention + V_bottom ----------------
__global__ __launch_bounds__(256) void k_out(const float* __restrict__ Q,
                                             const float* __restrict__ Kp,
                                             const float* __restrict__ Vp,
                                             const int* __restrict__ clusters,
                                             const int* __restrict__ topi,
                                             const float* __restrict__ abk,
                                             const float* __restrict__ Vg,
                                             float* __restrict__ out) {
    int tid = threadIdx.x, wid = tid >> 6, e = tid & 63;
    int q = blockIdx.x * 4 + wid;            // nh*LQ + l
    int nh = q >> 11, l = q & (LQ - 1);
    int n = nh >> 3, h = nh & 7;
    int c = clusters[q];
    float scale = 1.0f - abk[nh * CC + c];
    const int* ti = topi + (size_t)(nh * CC + c) * TK;
    float qe = Q[(((size_t)n * LQ + l) * HH + h) * EE + e];
    float myv = -INFINITY;
    for (int k = 0; k < TK; k++) {
        int idx = ti[k];
        float kv = Kp[(((size_t)n * SS + idx) * HH + h) * EE + e];
        float v = qe * kv;
        #pragma unroll
        for (int o = 32; o > 0; o >>= 1) v += __shfl_xor(v, o);
        if (e == k) myv = v;
    }
    float mv = myv;
    #pragma unroll
    for (int o = 32; o > 0; o >>= 1) { float v = __shfl_xor(mv, o); mv = v > mv ? v : mv; }
    float p = (e < TK) ? expf(0.125f * (myv - mv)) : 0.0f;
    float ssum = p;
    #pragma unroll
    for (int o = 32; o > 0; o >>= 1) ssum += __shfl_xor(ssum, o);
    float at = p / ssum * scale;
    float acc = 0.0f;
    for (int k = 0; k < TK; k++) {
        float wk = __shfl(at, k, 64);
        int idx = ti[k];
        acc += wk * Vp[(((size_t)n * SS + idx) * HH + h) * EE + e];
    }
    acc += Vg[(size_t)(nh * CC + c) * EE + e];
    out[(((size_t)n * LQ + l) * HH + h) * EE + e] = acc;
}

extern "C" void kernel_launch(void* const* d_in, const int* in_sizes, int n_in,
                              void* d_out, int out_size, void* d_ws, size_t ws_size,
                              hipStream_t stream) {
    const float* Q      = (const float*)d_in[0];
    const float* K      = (const float*)d_in[1];
    const float* V      = (const float*)d_in[2];
    const float* planes = (const float*)d_in[3];
    float* out = (float*)d_out;

    char* ws = (char*)d_ws;
    unsigned int* qmask    = (unsigned int*)(ws);                  // 128KB
    int*          clusters = (int*)(ws + (128 << 10));             // 128KB
    int*          counts   = (int*)(ws + (256 << 10));             // 16KB
    float*        abk      = (float*)(ws + (272 << 10));           // 16KB
    int*          topi     = (int*)(ws + (288 << 10));             // 512KB
    float*        Vg       = (float*)(ws + (800 << 10));           // 1MB
    double*       Qg       = (double*)(ws + (1824 << 10));         // 2MB

    k_hash<<<dim3(NH * LQ / 256), dim3(256), 0, stream>>>(Q, planes, qmask);
    k_kmeans<<<dim3(NH), dim3(256), 0, stream>>>(qmask, clusters, counts);
    k_qg<<<dim3(NH * 4), dim3(256), 0, stream>>>(Q, clusters, counts, Qg);
    k_rows<<<dim3(NH * CC), dim3(256), 0, stream>>>(K, V, Qg, topi, abk, Vg);
    k_out<<<dim3(NH * LQ / 4), dim3(256), 0, stream>>>(Q, K, V, clusters, topi, abk, Vg, out);
}

// Round 3
// 950.700 us; speedup vs baseline: 3.9837x; 1.3840x over previous
//
#include <hip/hip_runtime.h>
#include <math.h>
#include <float.h>

// Problem constants (from reference)
#define NB 2
#define LQ 2048
#define HH 8
#define EE 64
#define SS 2048
#define CC 256
#define KM_ITERS 10
#define NBITS 32
#define TK 32
#define NH (NB*HH)
#define CG 4    // clusters per k_rows block

// ---------------- K1: hash bits -> 32-bit mask per (n,h,l) ----------------
__global__ __launch_bounds__(256) void k_hash(const float* __restrict__ Q,
                                              const float* __restrict__ planes,
                                              unsigned int* __restrict__ qmask) {
    int gid = blockIdx.x * 256 + threadIdx.x;      // nh*LQ + l
    int nh = gid >> 11, l = gid & (LQ - 1);
    int n = nh >> 3, h = nh & 7;
    const float* qrow = Q + (((size_t)n * LQ + l) * HH + h) * EE;
    float q[64];
    #pragma unroll
    for (int e = 0; e < 64; e++) q[e] = qrow[e];
    unsigned int m = 0;
    for (int b = 0; b < NBITS; b++) {
        double acc = (double)planes[b * 65 + 64];   // bias
        #pragma unroll
        for (int e = 0; e < 64; e++) acc += (double)q[e] * (double)planes[b * 65 + e];
        if (acc > 0.0) m |= (1u << b);
    }
    qmask[gid] = m;
}

// ---------------- K2: k-means in Hamming space, exact integer ----------------
__global__ __launch_bounds__(256) void k_kmeans(const unsigned int* __restrict__ qmask,
                                                int* __restrict__ clusters,
                                                int* __restrict__ counts_out) {
    int nh = blockIdx.x;
    int t = threadIdx.x;
    __shared__ __align__(16) unsigned int cent[CC];
    __shared__ unsigned int qm[LQ];
    __shared__ unsigned int sorted[LQ];
    __shared__ int cnts[CC];
    __shared__ int scan[CC];
    __shared__ int cursor[CC];
    const unsigned int* qb = qmask + (size_t)nh * LQ;
    #pragma unroll
    for (int j = 0; j < 8; j++) qm[t + j * 256] = qb[t + j * 256];
    cent[t] = qb[t * 8];
    __syncthreads();
    unsigned int mym[8];
    #pragma unroll
    for (int j = 0; j < 8; j++) mym[j] = qm[t + j * 256];

    int bc[8];
    for (int it = 0; it <= KM_ITERS; ++it) {
        int bd[8];
        #pragma unroll
        for (int j = 0; j < 8; j++) { bd[j] = 1000; bc[j] = 0; }
        for (int c4 = 0; c4 < CC; c4 += 4) {
            uint4 cm = *(const uint4*)&cent[c4];
            #pragma unroll
            for (int j = 0; j < 8; j++) {
                int d0 = __popc(mym[j] ^ cm.x);
                int d1 = __popc(mym[j] ^ cm.y);
                int d2 = __popc(mym[j] ^ cm.z);
                int d3 = __popc(mym[j] ^ cm.w);
                if (d0 < bd[j]) { bd[j] = d0; bc[j] = c4; }
                if (d1 < bd[j]) { bd[j] = d1; bc[j] = c4 + 1; }
                if (d2 < bd[j]) { bd[j] = d2; bc[j] = c4 + 2; }
                if (d3 < bd[j]) { bd[j] = d3; bc[j] = c4 + 3; }
            }
        }
        if (it == KM_ITERS) break;

        cnts[t] = 0;
        __syncthreads();
        #pragma unroll
        for (int j = 0; j < 8; j++) atomicAdd(&cnts[bc[j]], 1);
        __syncthreads();
        scan[t] = cnts[t];
        __syncthreads();
        #pragma unroll
        for (int d = 1; d < CC; d <<= 1) {
            int v = scan[t];
            int add = (t >= d) ? scan[t - d] : 0;
            __syncthreads();
            scan[t] = v + add;
            __syncthreads();
        }
        int offt = scan[t] - cnts[t];
        cursor[t] = offt;
        __syncthreads();
        #pragma unroll
        for (int j = 0; j < 8; j++) {
            int pos = atomicAdd(&cursor[bc[j]], 1);
            sorted[pos] = mym[j];
        }
        __syncthreads();

        int cnt = cnts[t];
        if (cnt > 0) {
            int bs[32];
            #pragma unroll
            for (int b = 0; b < 32; b++) bs[b] = 0;
            for (int i = 0; i < cnt; i++) {
                unsigned int m = sorted[offt + i];
                #pragma unroll
                for (int b = 0; b < 32; b++) bs[b] += (m >> b) & 1;
            }
            unsigned int nc = 0;
            #pragma unroll
            for (int b = 0; b < 32; b++) if (2 * bs[b] >= cnt) nc |= (1u << b);
            cent[t] = nc;
        }
        __syncthreads();
    }

    cnts[t] = 0;
    __syncthreads();
    #pragma unroll
    for (int j = 0; j < 8; j++) {
        clusters[(size_t)nh * LQ + t + j * 256] = bc[j];
        atomicAdd(&cnts[bc[j]], 1);
    }
    __syncthreads();
    counts_out[nh * CC + t] = cnts[t];
}

// ---------------- K3: cluster-mean queries Qg (f64) ----------------
__global__ __launch_bounds__(256) void k_qg(const float* __restrict__ Q,
                                            const int* __restrict__ clusters,
                                            const int* __restrict__ counts,
                                            double* __restrict__ Qg) {
    int nh = blockIdx.x >> 2, eq = blockIdx.x & 3, e0 = eq * 16;
    int t = threadIdx.x;
    int n = nh >> 3, h = nh & 7;
    __shared__ int cl[LQ];
    for (int j = 0; j < 8; j++) cl[t + j * 256] = clusters[(size_t)nh * LQ + t + j * 256];
    __syncthreads();
    double acc[16];
    #pragma unroll
    for (int i = 0; i < 16; i++) acc[i] = 0.0;
    for (int p = 0; p < LQ; p++) {
        if (cl[p] == t) {
            const float* qr = Q + (((size_t)n * LQ + p) * HH + h) * EE + e0;
            #pragma unroll
            for (int i = 0; i < 16; i++) acc[i] += (double)qr[i];
        }
    }
    int cnt = counts[nh * CC + t];
    double safe = cnt > 0 ? (double)cnt : 1.0;
    double* o = Qg + ((size_t)(nh * CC + t)) * EE + e0;
    #pragma unroll
    for (int i = 0; i < 16; i++) o[i] = acc[i] / safe;
}

// ---------------- K3b: transpose K -> Kt[nh][e][s] ----------------
__global__ __launch_bounds__(256) void k_transpose(const float* __restrict__ Kp,
                                                   float* __restrict__ Kt) {
    int nh = blockIdx.x >> 5;            // 32 s-tiles of 64
    int s0 = (blockIdx.x & 31) * 64;
    int n = nh >> 3, h = nh & 7;
    __shared__ float tile[64][65];
    int t = threadIdx.x;
    int e = t & 63, r0 = t >> 6;
    #pragma unroll
    for (int j = 0; j < 16; j++) {
        int r = r0 * 16 + j;
        tile[r][e] = Kp[(((size_t)n * SS + s0 + r) * HH + h) * EE + e];
    }
    __syncthreads();
    int sl = t & 63, eg = t >> 6;
    #pragma unroll
    for (int j = 0; j < 16; j++) {
        int ee_ = eg * 16 + j;
        Kt[((size_t)nh * EE + ee_) * SS + s0 + sl] = tile[sl][ee_];
    }
}

// ---------------- K4 v2: 4 clusters/block; coalesced Kt; in-register top-k ----------------
__global__ __launch_bounds__(256) void k_rows(const float* __restrict__ Kt,
                                              const float* __restrict__ Vp,
                                              const double* __restrict__ Qg,
                                              int* __restrict__ topi,
                                              float* __restrict__ abk,
                                              float* __restrict__ Vg) {
    int bid = blockIdx.x;
    int nh = bid >> 6, cg = bid & 63;
    int c0 = cg * CG;
    int n = nh >> 3, h = nh & 7;
    int t = threadIdx.x, w = t >> 6, l = t & 63;

    __shared__ double xrow[CG][SS];        // 64KB; overlaid later
    __shared__ double qgl[EE][CG];         // 2KB
    float* wpack = (float*)&xrow[0][0];    // [SS][CG] f32 = 32KB (xrow[0..1])
    float* redv  = (float*)&xrow[2][0];    // 4KB (xrow[2] region, disjoint)

    // qg: [e][c] for broadcast reads
    qgl[t >> 2][t & 3] = Qg[((size_t)(nh * CC + c0 + (t & 3))) * EE + (t >> 2)];
    __syncthreads();

    // ---- phase A: QK scores (f64), coalesced Kt reads, 32 indep accumulators ----
    double acc[8][CG];
    #pragma unroll
    for (int r = 0; r < 8; r++)
        #pragma unroll
        for (int c = 0; c < CG; c++) acc[r][c] = 0.0;
    const float* ktb = Kt + ((size_t)nh * EE) * SS + t;
    for (int e = 0; e < EE; e++) {
        double q0 = qgl[e][0], q1 = qgl[e][1], q2 = qgl[e][2], q3 = qgl[e][3];
        const float* kr = ktb + (size_t)e * SS;
        #pragma unroll
        for (int r = 0; r < 8; r++) {
            double kv = (double)kr[r * 256];
            acc[r][0] += q0 * kv; acc[r][1] += q1 * kv;
            acc[r][2] += q2 * kv; acc[r][3] += q3 * kv;
        }
    }
    #pragma unroll
    for (int r = 0; r < 8; r++)
        #pragma unroll
        for (int c = 0; c < CG; c++) xrow[c][t + r * 256] = acc[r][c];
    __syncthreads();

    // ---- phase B: per-wave row (c = w): max, denom, top-32, weights ----
    double v[32];
    #pragma unroll
    for (int k = 0; k < 32; k++) v[k] = xrow[w][l + k * 64];

    double m = v[0];
    #pragma unroll
    for (int k = 1; k < 32; k++) m = v[k] > m ? v[k] : m;
    #pragma unroll
    for (int o = 32; o > 0; o >>= 1) { double z = __shfl_xor(m, o); m = z > m ? z : m; }

    double ds = 0.0;
    #pragma unroll
    for (int k = 0; k < 32; k++) ds += (double)expf(0.125f * (float)(v[k] - m));
    #pragma unroll
    for (int o = 32; o > 0; o >>= 1) ds += __shfl_xor(ds, o);

    // selection: iterated argmax, strict order ties -> lowest s (matches lax.top_k)
    unsigned ext = 0;
    double lbv = -1e301; int lbi = 1 << 30;
    #pragma unroll
    for (int k = 0; k < 32; k++)
        if (v[k] > lbv) { lbv = v[k]; lbi = l + k * 64; }
    double topsum = 0.0;
    int rowid = nh * CC + c0 + w;
    for (int kk = 0; kk < TK; kk++) {
        double bv = lbv; int bi = lbi;
        #pragma unroll
        for (int o = 32; o > 0; o >>= 1) {
            double v2 = __shfl_xor(bv, o); int i2 = __shfl_xor(bi, o);
            if (v2 > bv || (v2 == bv && i2 < bi)) { bv = v2; bi = i2; }
        }
        topsum += (double)expf(0.125f * (float)(bv - m));
        if (l == 0) topi[(size_t)rowid * TK + kk] = bi;
        if ((bi & 63) == l) {             // this lane owned the winner
            ext |= 1u << (bi >> 6);
            lbv = -1e301; lbi = 1 << 30;
            #pragma unroll
            for (int k = 0; k < 32; k++)
                if (!((ext >> k) & 1) && v[k] > lbv) { lbv = v[k]; lbi = l + k * 64; }
        }
    }
    if (l == 0) abk[rowid] = (float)((ds - topsum) / ds);
    __syncthreads();   // all xrow reads complete before wpack overlay writes

    float invd = (float)(1.0 / ds);
    #pragma unroll
    for (int k = 0; k < 32; k++) {
        float wk = ((ext >> k) & 1) ? 0.0f
                 : expf(0.125f * (float)(v[k] - m)) * invd;
        wpack[(l + k * 64) * CG + w] = wk;
    }
    __syncthreads();

    // ---- phase C: Vg = W x V, coalesced V reads, f32 accumulate ----
    {
        int e = l, grp = w;
        float a0 = 0, a1 = 0, a2 = 0, a3 = 0;
        const float* vb = Vp + (((size_t)n * SS) * HH + h) * EE + e;
        const float4* wp4 = (const float4*)wpack;
        for (int s = grp * 512; s < grp * 512 + 512; s++) {
            float4 wv = wp4[s];
            float vv = vb[(size_t)s * HH * EE];
            a0 += wv.x * vv; a1 += wv.y * vv; a2 += wv.z * vv; a3 += wv.w * vv;
        }
        // redv region (xrow[2]) disjoint from wpack (xrow[0..1]) -> no barrier needed
        redv[(grp * 4 + 0) * 64 + e] = a0;
        redv[(grp * 4 + 1) * 64 + e] = a1;
        redv[(grp * 4 + 2) * 64 + e] = a2;
        redv[(grp * 4 + 3) * 64 + e] = a3;
        __syncthreads();
        int c = w;
        float s = redv[(0 * 4 + c) * 64 + e] + redv[(1 * 4 + c) * 64 + e]
                + redv[(2 * 4 + c) * 64 + e] + redv[(3 * 4 + c) * 64 + e];
        Vg[((size_t)(nh * CC + c0 + c)) * EE + e] = s;
    }
}

// ---------------- K5: per-query top-32 re-attention + V_bottom ----------------
__global__ __launch_bounds__(256) void k_out(const float* __restrict__ Q,
                                             const float* __restrict__ Kp,
                                             const float* __restrict__ Vp,
                                             const int* __restrict__ clusters,
                                             const int* __restrict__ topi,
                                             const float* __restrict__ abk,
                                             const float* __restrict__ Vg,
                                             float* __restrict__ out) {
    int tid = threadIdx.x, wid = tid >> 6, e = tid & 63;
    int q = blockIdx.x * 4 + wid;            // nh*LQ + l
    int nh = q >> 11, l = q & (LQ - 1);
    int n = nh >> 3, h = nh & 7;
    int c = clusters[q];
    float scale = 1.0f - abk[nh * CC + c];
    const int* ti = topi + (size_t)(nh * CC + c) * TK;
    float qe = Q[(((size_t)n * LQ + l) * HH + h) * EE + e];
    float myv = -INFINITY;
    for (int k = 0; k < TK; k++) {
        int idx = ti[k];
        float kv = Kp[(((size_t)n * SS + idx) * HH + h) * EE + e];
        float v = qe * kv;
        #pragma unroll
        for (int o = 32; o > 0; o >>= 1) v += __shfl_xor(v, o);
        if (e == k) myv = v;
    }
    float mv = myv;
    #pragma unroll
    for (int o = 32; o > 0; o >>= 1) { float v = __shfl_xor(mv, o); mv = v > mv ? v : mv; }
    float p = (e < TK) ? expf(0.125f * (myv - mv)) : 0.0f;
    float ssum = p;
    #pragma unroll
    for (int o = 32; o > 0; o >>= 1) ssum += __shfl_xor(ssum, o);
    float at = p / ssum * scale;
    float acc = 0.0f;
    for (int k = 0; k < TK; k++) {
        float wk = __shfl(at, k, 64);
        int idx = ti[k];
        acc += wk * Vp[(((size_t)n * SS + idx) * HH + h) * EE + e];
    }
    acc += Vg[(size_t)(nh * CC + c) * EE + e];
    out[(((size_t)n * LQ + l) * HH + h) * EE + e] = acc;
}

extern "C" void kernel_launch(void* const* d_in, const int* in_sizes, int n_in,
                              void* d_out, int out_size, void* d_ws, size_t ws_size,
                              hipStream_t stream) {
    const float* Q      = (const float*)d_in[0];
    const float* K      = (const float*)d_in[1];
    const float* V      = (const float*)d_in[2];
    const float* planes = (const float*)d_in[3];
    float* out = (float*)d_out;

    char* ws = (char*)d_ws;
    unsigned int* qmask    = (unsigned int*)(ws);                  // 128KB
    int*          clusters = (int*)(ws + (128 << 10));             // 128KB
    int*          counts   = (int*)(ws + (256 << 10));             // 16KB
    float*        abk      = (float*)(ws + (272 << 10));           // 16KB
    int*          topi     = (int*)(ws + (288 << 10));             // 512KB
    float*        Vg       = (float*)(ws + (800 << 10));           // 1MB
    double*       Qg       = (double*)(ws + (1824 << 10));         // 2MB
    float*        Kt       = (float*)(ws + (4096 << 10));          // 8.4MB (Kt[nh][e][s])

    k_transpose<<<dim3(NH * 32), dim3(256), 0, stream>>>(K, Kt);
    k_hash<<<dim3(NH * LQ / 256), dim3(256), 0, stream>>>(Q, planes, qmask);
    k_kmeans<<<dim3(NH), dim3(256), 0, stream>>>(qmask, clusters, counts);
    k_qg<<<dim3(NH * 4), dim3(256), 0, stream>>>(Q, clusters, counts, Qg);
    k_rows<<<dim3(NH * CC / CG), dim3(256), 0, stream>>>(Kt, V, Qg, topi, abk, Vg);
    k_out<<<dim3(NH * LQ / 4), dim3(256), 0, stream>>>(Q, K, V, clusters, topi, abk, Vg, out);
}

// Round 4
// 652.466 us; speedup vs baseline: 5.8045x; 1.4571x over previous
//
#include <hip/hip_runtime.h>
#include <math.h>
#include <float.h>

// Problem constants (from reference)
#define NB 2
#define LQ 2048
#define HH 8
#define EE 64
#define SS 2048
#define CC 256
#define KM_ITERS 10
#define NBITS 32
#define TK 32
#define NH (NB*HH)
#define CG 4    // clusters per k_rows block

// ---------------- K1: hash bits -> 32-bit mask per (n,h,l) ----------------
__global__ __launch_bounds__(256) void k_hash(const float* __restrict__ Q,
                                              const float* __restrict__ planes,
                                              unsigned int* __restrict__ qmask) {
    int gid = blockIdx.x * 256 + threadIdx.x;      // nh*LQ + l
    int nh = gid >> 11, l = gid & (LQ - 1);
    int n = nh >> 3, h = nh & 7;
    const float* qrow = Q + (((size_t)n * LQ + l) * HH + h) * EE;
    float q[64];
    #pragma unroll
    for (int e = 0; e < 64; e++) q[e] = qrow[e];
    unsigned int m = 0;
    for (int b = 0; b < NBITS; b++) {
        double acc = (double)planes[b * 65 + 64];   // bias
        #pragma unroll
        for (int e = 0; e < 64; e++) acc += (double)q[e] * (double)planes[b * 65 + e];
        if (acc > 0.0) m |= (1u << b);
    }
    qmask[gid] = m;
}

// ---------------- K2: k-means in Hamming space, exact integer ----------------
// Emits final counting-sorted order + offsets for the segmented Qg kernel.
__global__ __launch_bounds__(256) void k_kmeans(const unsigned int* __restrict__ qmask,
                                                int* __restrict__ clusters,
                                                int* __restrict__ counts_out,
                                                int* __restrict__ order_out,
                                                int* __restrict__ offsets_out) {
    int nh = blockIdx.x;
    int t = threadIdx.x;
    __shared__ __align__(16) unsigned int cent[CC];
    __shared__ unsigned int qm[LQ];
    __shared__ unsigned int sorted[LQ];
    __shared__ int cnts[CC];
    __shared__ int scan[CC];
    __shared__ int cursor[CC];
    const unsigned int* qb = qmask + (size_t)nh * LQ;
    #pragma unroll
    for (int j = 0; j < 8; j++) qm[t + j * 256] = qb[t + j * 256];
    cent[t] = qb[t * 8];                   // init_idx = c*8
    __syncthreads();
    unsigned int mym[8];
    #pragma unroll
    for (int j = 0; j < 8; j++) mym[j] = qm[t + j * 256];

    int bc[8];
    for (int it = 0; it <= KM_ITERS; ++it) {
        int bd[8];
        #pragma unroll
        for (int j = 0; j < 8; j++) { bd[j] = 1000; bc[j] = 0; }
        for (int c4 = 0; c4 < CC; c4 += 4) {
            uint4 cm = *(const uint4*)&cent[c4];
            #pragma unroll
            for (int j = 0; j < 8; j++) {
                int d0 = __popc(mym[j] ^ cm.x);
                int d1 = __popc(mym[j] ^ cm.y);
                int d2 = __popc(mym[j] ^ cm.z);
                int d3 = __popc(mym[j] ^ cm.w);
                if (d0 < bd[j]) { bd[j] = d0; bc[j] = c4; }
                if (d1 < bd[j]) { bd[j] = d1; bc[j] = c4 + 1; }
                if (d2 < bd[j]) { bd[j] = d2; bc[j] = c4 + 2; }
                if (d3 < bd[j]) { bd[j] = d3; bc[j] = c4 + 3; }
            }
        }
        if (it == KM_ITERS) break;

        cnts[t] = 0;
        __syncthreads();
        #pragma unroll
        for (int j = 0; j < 8; j++) atomicAdd(&cnts[bc[j]], 1);
        __syncthreads();
        scan[t] = cnts[t];
        __syncthreads();
        #pragma unroll
        for (int d = 1; d < CC; d <<= 1) {
            int v = scan[t];
            int add = (t >= d) ? scan[t - d] : 0;
            __syncthreads();
            scan[t] = v + add;
            __syncthreads();
        }
        int offt = scan[t] - cnts[t];
        cursor[t] = offt;
        __syncthreads();
        #pragma unroll
        for (int j = 0; j < 8; j++) {
            int pos = atomicAdd(&cursor[bc[j]], 1);
            sorted[pos] = mym[j];
        }
        __syncthreads();

        int cnt = cnts[t];
        if (cnt > 0) {
            int bs[32];
            #pragma unroll
            for (int b = 0; b < 32; b++) bs[b] = 0;
            for (int i = 0; i < cnt; i++) {
                unsigned int m = sorted[offt + i];
                #pragma unroll
                for (int b = 0; b < 32; b++) bs[b] += (m >> b) & 1;
            }
            unsigned int nc = 0;
            #pragma unroll
            for (int b = 0; b < 32; b++) if (2 * bs[b] >= cnt) nc |= (1u << b);
            cent[t] = nc;                  // exact majority: 2*sum >= cnt
        }
        __syncthreads();
    }

    // ---- final: assignment, counts, sorted order + offsets ----
    cnts[t] = 0;
    __syncthreads();
    #pragma unroll
    for (int j = 0; j < 8; j++) {
        clusters[(size_t)nh * LQ + t + j * 256] = bc[j];
        atomicAdd(&cnts[bc[j]], 1);
    }
    __syncthreads();
    scan[t] = cnts[t];
    __syncthreads();
    #pragma unroll
    for (int d = 1; d < CC; d <<= 1) {
        int v = scan[t];
        int add = (t >= d) ? scan[t - d] : 0;
        __syncthreads();
        scan[t] = v + add;
        __syncthreads();
    }
    int offt = scan[t] - cnts[t];
    cursor[t] = offt;
    counts_out[nh * CC + t] = cnts[t];
    offsets_out[nh * CC + t] = offt;
    __syncthreads();
    #pragma unroll
    for (int j = 0; j < 8; j++) {
        int pos = atomicAdd(&cursor[bc[j]], 1);
        order_out[(size_t)nh * LQ + pos] = t + j * 256;
    }
}

// ---------------- K3 v2: segmented cluster-mean Qg (f64), wave per cluster ----------------
__global__ __launch_bounds__(256) void k_qg(const float* __restrict__ Q,
                                            const int* __restrict__ order,
                                            const int* __restrict__ offsets,
                                            const int* __restrict__ counts,
                                            double* __restrict__ Qg) {
    int nh = blockIdx.x >> 6;              // 64 blocks per nh
    int c = (blockIdx.x & 63) * 4 + (threadIdx.x >> 6);
    int e = threadIdx.x & 63;
    int n = nh >> 3, h = nh & 7;
    int off = offsets[nh * CC + c];
    int cnt = counts[nh * CC + c];
    const int* ord = order + (size_t)nh * LQ + off;
    double acc = 0.0;
    for (int i = 0; i < cnt; i++) {
        int p = ord[i];                    // wave-uniform broadcast read
        acc += (double)Q[(((size_t)n * LQ + p) * HH + h) * EE + e];
    }
    double safe = cnt > 0 ? (double)cnt : 1.0;
    Qg[((size_t)(nh * CC + c)) * EE + e] = acc / safe;
}

// ---------------- K3b: transpose K -> Kt[nh][e][s] ----------------
__global__ __launch_bounds__(256) void k_transpose(const float* __restrict__ Kp,
                                                   float* __restrict__ Kt) {
    int nh = blockIdx.x >> 5;              // 32 s-tiles of 64
    int s0 = (blockIdx.x & 31) * 64;
    int n = nh >> 3, h = nh & 7;
    __shared__ float tile[64][65];
    int t = threadIdx.x;
    int e = t & 63, r0 = t >> 6;
    #pragma unroll
    for (int j = 0; j < 16; j++) {
        int r = r0 * 16 + j;
        tile[r][e] = Kp[(((size_t)n * SS + s0 + r) * HH + h) * EE + e];
    }
    __syncthreads();
    int sl = t & 63, eg = t >> 6;
    #pragma unroll
    for (int j = 0; j < 16; j++) {
        int ee_ = eg * 16 + j;
        Kt[((size_t)nh * EE + ee_) * SS + s0 + sl] = tile[sl][ee_];
    }
}

// ---------------- K4: 4 clusters/block; coalesced Kt; in-register top-k ----------------
__global__ __launch_bounds__(256) void k_rows(const float* __restrict__ Kt,
                                              const float* __restrict__ Vp,
                                              const double* __restrict__ Qg,
                                              int* __restrict__ topi,
                                              float* __restrict__ abk,
                                              float* __restrict__ Vg) {
    int bid = blockIdx.x;
    int nh = bid >> 6, cg = bid & 63;
    int c0 = cg * CG;
    int n = nh >> 3, h = nh & 7;
    int t = threadIdx.x, w = t >> 6, l = t & 63;

    __shared__ double xrow[CG][SS];        // 64KB; overlaid later
    __shared__ double qgl[EE][CG];         // 2KB
    float* wpack = (float*)&xrow[0][0];    // [SS][CG] f32 = 32KB (xrow[0..1])
    float* redv  = (float*)&xrow[2][0];    // 4KB (xrow[2] region, disjoint)

    qgl[t >> 2][t & 3] = Qg[((size_t)(nh * CC + c0 + (t & 3))) * EE + (t >> 2)];
    __syncthreads();

    // ---- phase A: QK scores (f64), coalesced Kt reads ----
    double acc[8][CG];
    #pragma unroll
    for (int r = 0; r < 8; r++)
        #pragma unroll
        for (int c = 0; c < CG; c++) acc[r][c] = 0.0;
    const float* ktb = Kt + ((size_t)nh * EE) * SS + t;
    for (int e = 0; e < EE; e++) {
        double q0 = qgl[e][0], q1 = qgl[e][1], q2 = qgl[e][2], q3 = qgl[e][3];
        const float* kr = ktb + (size_t)e * SS;
        #pragma unroll
        for (int r = 0; r < 8; r++) {
            double kv = (double)kr[r * 256];
            acc[r][0] += q0 * kv; acc[r][1] += q1 * kv;
            acc[r][2] += q2 * kv; acc[r][3] += q3 * kv;
        }
    }
    #pragma unroll
    for (int r = 0; r < 8; r++)
        #pragma unroll
        for (int c = 0; c < CG; c++) xrow[c][t + r * 256] = acc[r][c];
    __syncthreads();

    // ---- phase B: per-wave row (c = w): max, denom, top-32, weights ----
    double v[32];
    #pragma unroll
    for (int k = 0; k < 32; k++) v[k] = xrow[w][l + k * 64];

    double m = v[0];
    #pragma unroll
    for (int k = 1; k < 32; k++) m = v[k] > m ? v[k] : m;
    #pragma unroll
    for (int o = 32; o > 0; o >>= 1) { double z = __shfl_xor(m, o); m = z > m ? z : m; }

    double ds = 0.0;
    #pragma unroll
    for (int k = 0; k < 32; k++) ds += (double)expf(0.125f * (float)(v[k] - m));
    #pragma unroll
    for (int o = 32; o > 0; o >>= 1) ds += __shfl_xor(ds, o);

    unsigned ext = 0;
    double lbv = -1e301; int lbi = 1 << 30;
    #pragma unroll
    for (int k = 0; k < 32; k++)
        if (v[k] > lbv) { lbv = v[k]; lbi = l + k * 64; }
    double topsum = 0.0;
    int rowid = nh * CC + c0 + w;
    for (int kk = 0; kk < TK; kk++) {
        double bv = lbv; int bi = lbi;
        #pragma unroll
        for (int o = 32; o > 0; o >>= 1) {
            double v2 = __shfl_xor(bv, o); int i2 = __shfl_xor(bi, o);
            if (v2 > bv || (v2 == bv && i2 < bi)) { bv = v2; bi = i2; }
        }
        topsum += (double)expf(0.125f * (float)(bv - m));
        if (l == 0) topi[(size_t)rowid * TK + kk] = bi;
        if ((bi & 63) == l) {
            ext |= 1u << (bi >> 6);
            lbv = -1e301; lbi = 1 << 30;
            #pragma unroll
            for (int k = 0; k < 32; k++)
                if (!((ext >> k) & 1) && v[k] > lbv) { lbv = v[k]; lbi = l + k * 64; }
        }
    }
    if (l == 0) abk[rowid] = (float)((ds - topsum) / ds);
    __syncthreads();

    float invd = (float)(1.0 / ds);
    #pragma unroll
    for (int k = 0; k < 32; k++) {
        float wk = ((ext >> k) & 1) ? 0.0f
                 : expf(0.125f * (float)(v[k] - m)) * invd;
        wpack[(l + k * 64) * CG + w] = wk;
    }
    __syncthreads();

    // ---- phase C: Vg = W x V, coalesced V reads, f32 accumulate ----
    {
        int e = l, grp = w;
        float a0 = 0, a1 = 0, a2 = 0, a3 = 0;
        const float* vb = Vp + (((size_t)n * SS) * HH + h) * EE + e;
        const float4* wp4 = (const float4*)wpack;
        for (int s = grp * 512; s < grp * 512 + 512; s++) {
            float4 wv = wp4[s];
            float vv = vb[(size_t)s * HH * EE];
            a0 += wv.x * vv; a1 += wv.y * vv; a2 += wv.z * vv; a3 += wv.w * vv;
        }
        redv[(grp * 4 + 0) * 64 + e] = a0;
        redv[(grp * 4 + 1) * 64 + e] = a1;
        redv[(grp * 4 + 2) * 64 + e] = a2;
        redv[(grp * 4 + 3) * 64 + e] = a3;
        __syncthreads();
        int c = w;
        float s = redv[(0 * 4 + c) * 64 + e] + redv[(1 * 4 + c) * 64 + e]
                + redv[(2 * 4 + c) * 64 + e] + redv[(3 * 4 + c) * 64 + e];
        Vg[((size_t)(nh * CC + c0 + c)) * EE + e] = s;
    }
}

// ---------------- K5: per-query top-32 re-attention + V_bottom ----------------
__global__ __launch_bounds__(256) void k_out(const float* __restrict__ Q,
                                             const float* __restrict__ Kp,
                                             const float* __restrict__ Vp,
                                             const int* __restrict__ clusters,
                                             const int* __restrict__ topi,
                                             const float* __restrict__ abk,
                                             const float* __restrict__ Vg,
                                             float* __restrict__ out) {
    int tid = threadIdx.x, wid = tid >> 6, e = tid & 63;
    int q = blockIdx.x * 4 + wid;            // nh*LQ + l
    int nh = q >> 11, l = q & (LQ - 1);
    int n = nh >> 3, h = nh & 7;
    int c = clusters[q];
    float scale = 1.0f - abk[nh * CC + c];
    const int* ti = topi + (size_t)(nh * CC + c) * TK;
    float qe = Q[(((size_t)n * LQ + l) * HH + h) * EE + e];
    float myv = -INFINITY;
    for (int k = 0; k < TK; k++) {
        int idx = ti[k];
        float kv = Kp[(((size_t)n * SS + idx) * HH + h) * EE + e];
        float v = qe * kv;
        #pragma unroll
        for (int o = 32; o > 0; o >>= 1) v += __shfl_xor(v, o);
        if (e == k) myv = v;
    }
    float mv = myv;
    #pragma unroll
    for (int o = 32; o > 0; o >>= 1) { float v = __shfl_xor(mv, o); mv = v > mv ? v : mv; }
    float p = (e < TK) ? expf(0.125f * (myv - mv)) : 0.0f;
    float ssum = p;
    #pragma unroll
    for (int o = 32; o > 0; o >>= 1) ssum += __shfl_xor(ssum, o);
    float at = p / ssum * scale;
    float acc = 0.0f;
    for (int k = 0; k < TK; k++) {
        float wk = __shfl(at, k, 64);
        int idx = ti[k];
        acc += wk * Vp[(((size_t)n * SS + idx) * HH + h) * EE + e];
    }
    acc += Vg[(size_t)(nh * CC + c) * EE + e];
    out[(((size_t)n * LQ + l) * HH + h) * EE + e] = acc;
}

extern "C" void kernel_launch(void* const* d_in, const int* in_sizes, int n_in,
                              void* d_out, int out_size, void* d_ws, size_t ws_size,
                              hipStream_t stream) {
    const float* Q      = (const float*)d_in[0];
    const float* K      = (const float*)d_in[1];
    const float* V      = (const float*)d_in[2];
    const float* planes = (const float*)d_in[3];
    float* out = (float*)d_out;

    char* ws = (char*)d_ws;
    unsigned int* qmask    = (unsigned int*)(ws);                   // 128KB
    int*          clusters = (int*)(ws + (128 << 10));              // 128KB
    int*          counts   = (int*)(ws + (256 << 10));              // 16KB
    float*        abk      = (float*)(ws + (272 << 10));            // 16KB
    int*          topi     = (int*)(ws + (288 << 10));              // 512KB
    float*        Vg       = (float*)(ws + (800 << 10));            // 1MB
    double*       Qg       = (double*)(ws + (1824 << 10));          // 2MB
    float*        Kt       = (float*)(ws + (4096 << 10));           // 8MB  [4MB,12MB)
    int*          order    = (int*)(ws + (12288 << 10));            // 128KB
    int*          offsets  = (int*)(ws + (12416 << 10));            // 16KB

    k_transpose<<<dim3(NH * 32), dim3(256), 0, stream>>>(K, Kt);
    k_hash<<<dim3(NH * LQ / 256), dim3(256), 0, stream>>>(Q, planes, qmask);
    k_kmeans<<<dim3(NH), dim3(256), 0, stream>>>(qmask, clusters, counts, order, offsets);
    k_qg<<<dim3(NH * 64), dim3(256), 0, stream>>>(Q, order, offsets, counts, Qg);
    k_rows<<<dim3(NH * CC / CG), dim3(256), 0, stream>>>(Kt, V, Qg, topi, abk, Vg);
    k_out<<<dim3(NH * LQ / 4), dim3(256), 0, stream>>>(Q, K, V, clusters, topi, abk, Vg, out);
}

// Round 5
// 567.405 us; speedup vs baseline: 6.6747x; 1.1499x over previous
//
#include <hip/hip_runtime.h>
#include <math.h>
#include <float.h>

// Problem constants (from reference)
#define NB 2
#define LQ 2048
#define HH 8
#define EE 64
#define SS 2048
#define CC 256
#define KM_ITERS 10
#define NBITS 32
#define TK 32
#define NH (NB*HH)
#define CG 4    // clusters per k_rows block

// ---------------- K1: hash bits -> 32-bit mask per (n,h,l) ----------------
__global__ __launch_bounds__(256) void k_hash(const float* __restrict__ Q,
                                              const float* __restrict__ planes,
                                              unsigned int* __restrict__ qmask) {
    int gid = blockIdx.x * 256 + threadIdx.x;      // nh*LQ + l
    int nh = gid >> 11, l = gid & (LQ - 1);
    int n = nh >> 3, h = nh & 7;
    const float* qrow = Q + (((size_t)n * LQ + l) * HH + h) * EE;
    float q[64];
    #pragma unroll
    for (int e = 0; e < 64; e++) q[e] = qrow[e];
    unsigned int m = 0;
    for (int b = 0; b < NBITS; b++) {
        double acc = (double)planes[b * 65 + 64];   // bias
        #pragma unroll
        for (int e = 0; e < 64; e++) acc += (double)q[e] * (double)planes[b * 65 + e];
        if (acc > 0.0) m |= (1u << b);
    }
    qmask[gid] = m;
}

// ---------------- K2 v3: k-means, 512 threads, packed-min assign, shfl scan ----------------
// All decisions exact-integer: dist = popc(x^c) packed as (d<<8)|c, min => first-min
// tie-break identical to jnp.argmin; centroid majority 2*sum >= cnt exact.
__global__ __launch_bounds__(512) void k_kmeans(const unsigned int* __restrict__ qmask,
                                                int* __restrict__ clusters,
                                                int* __restrict__ counts_out,
                                                int* __restrict__ order_out,
                                                int* __restrict__ offsets_out) {
    int nh = blockIdx.x;
    int t = threadIdx.x;
    __shared__ __align__(16) unsigned int cent[CC];   // 1KB
    __shared__ unsigned int sorted[LQ];               // 8KB (bits, cluster-grouped)
    __shared__ int cnts[CC];                          // 1KB
    __shared__ int offs[CC];                          // 1KB
    __shared__ int cursor[CC];                        // 1KB

    const unsigned int* qb = qmask + (size_t)nh * LQ;
    unsigned int mym[4];
    #pragma unroll
    for (int k = 0; k < 4; k++) mym[k] = qb[t + k * 512];
    if (t < CC) { cent[t] = qb[t * 8]; cnts[t] = 0; }   // init_idx = c*8
    __syncthreads();

    int bc[4];
    for (int it = 0; it <= KM_ITERS; ++it) {
        // ---- assign: 3 VALU/candidate, ties -> lowest c via packed min ----
        int best[4];
        #pragma unroll
        for (int k = 0; k < 4; k++) best[k] = 0x7fffffff;
        const uint4* cent4 = (const uint4*)cent;
        for (int c4 = 0; c4 < CC / 4; c4++) {
            uint4 cm = cent4[c4];
            int base = c4 << 2;
            #pragma unroll
            for (int q = 0; q < 4; q++) {
                unsigned int cmq = (&cm.x)[q];
                #pragma unroll
                for (int k = 0; k < 4; k++) {
                    int d = __popc(mym[k] ^ cmq);
                    int cand = (d << 8) + (base + q);
                    best[k] = best[k] < cand ? best[k] : cand;
                }
            }
        }
        #pragma unroll
        for (int k = 0; k < 4; k++) bc[k] = best[k] & 255;
        if (it == KM_ITERS) break;

        // ---- counts ----
        #pragma unroll
        for (int k = 0; k < 4; k++) atomicAdd(&cnts[bc[k]], 1);
        __syncthreads();                               // A
        // ---- single-wave exclusive scan (t < 64), 4 clusters/lane ----
        if (t < 64) {
            int c0 = cnts[4 * t], c1 = cnts[4 * t + 1], c2 = cnts[4 * t + 2], c3 = cnts[4 * t + 3];
            int s1 = c0 + c1, s2 = s1 + c2, tot = s2 + c3;
            int inc = tot;
            #pragma unroll
            for (int o = 1; o < 64; o <<= 1) {
                int v = __shfl_up(inc, o);
                if (t >= o) inc += v;
            }
            int excl = inc - tot;
            offs[4 * t] = excl;        cursor[4 * t] = excl;
            offs[4 * t + 1] = excl + c0; cursor[4 * t + 1] = excl + c0;
            offs[4 * t + 2] = excl + s1; cursor[4 * t + 2] = excl + s1;
            offs[4 * t + 3] = excl + s2; cursor[4 * t + 3] = excl + s2;
        }
        __syncthreads();                               // B
        int cl = t >> 1, j = t & 1;                    // update ownership (read before scatter)
        int cnt_c = cnts[cl], off_c = offs[cl];
        // ---- scatter bits, cluster-grouped ----
        #pragma unroll
        for (int k = 0; k < 4; k++) {
            int pos = atomicAdd(&cursor[bc[k]], 1);
            sorted[pos] = mym[k];
        }
        __syncthreads();                               // C
        // ---- update: 2 lanes per cluster, balanced expand + shfl combine ----
        int bs[32];
        #pragma unroll
        for (int b = 0; b < 32; b++) bs[b] = 0;
        for (int i = j; i < cnt_c; i += 2) {
            unsigned int m = sorted[off_c + i];
            #pragma unroll
            for (int b = 0; b < 32; b++) bs[b] += (m >> b) & 1;
        }
        #pragma unroll
        for (int b = 0; b < 32; b++) bs[b] += __shfl_xor(bs[b], 1);
        if (j == 0 && cnt_c > 0) {
            unsigned int nc = 0;
            #pragma unroll
            for (int b = 0; b < 32; b++) if (2 * bs[b] >= cnt_c) nc |= (1u << b);
            cent[cl] = nc;                             // exact majority
        }
        if (t < CC) cnts[t] = 0;                       // next-iter atomics are after barrier E
        __syncthreads();                               // E
    }

    // ---- final: assignment, counts, offsets, sorted order (indices) ----
    #pragma unroll
    for (int k = 0; k < 4; k++) {
        clusters[(size_t)nh * LQ + t + k * 512] = bc[k];
        atomicAdd(&cnts[bc[k]], 1);
    }
    __syncthreads();
    if (t < 64) {
        int c0 = cnts[4 * t], c1 = cnts[4 * t + 1], c2 = cnts[4 * t + 2], c3 = cnts[4 * t + 3];
        int s1 = c0 + c1, s2 = s1 + c2, tot = s2 + c3;
        int inc = tot;
        #pragma unroll
        for (int o = 1; o < 64; o <<= 1) {
            int v = __shfl_up(inc, o);
            if (t >= o) inc += v;
        }
        int excl = inc - tot;
        offs[4 * t] = excl;          cursor[4 * t] = excl;
        offs[4 * t + 1] = excl + c0; cursor[4 * t + 1] = excl + c0;
        offs[4 * t + 2] = excl + s1; cursor[4 * t + 2] = excl + s1;
        offs[4 * t + 3] = excl + s2; cursor[4 * t + 3] = excl + s2;
    }
    __syncthreads();
    if (t < CC) {
        counts_out[nh * CC + t] = cnts[t];
        offsets_out[nh * CC + t] = offs[t];
    }
    #pragma unroll
    for (int k = 0; k < 4; k++) {
        int pos = atomicAdd(&cursor[bc[k]], 1);
        order_out[(size_t)nh * LQ + pos] = t + k * 512;
    }
}

// ---------------- K3: segmented cluster-mean Qg (f64), wave per cluster ----------------
__global__ __launch_bounds__(256) void k_qg(const float* __restrict__ Q,
                                            const int* __restrict__ order,
                                            const int* __restrict__ offsets,
                                            const int* __restrict__ counts,
                                            double* __restrict__ Qg) {
    int nh = blockIdx.x >> 6;              // 64 blocks per nh
    int c = (blockIdx.x & 63) * 4 + (threadIdx.x >> 6);
    int e = threadIdx.x & 63;
    int n = nh >> 3, h = nh & 7;
    int off = offsets[nh * CC + c];
    int cnt = counts[nh * CC + c];
    const int* ord = order + (size_t)nh * LQ + off;
    double acc = 0.0;
    for (int i = 0; i < cnt; i++) {
        int p = ord[i];                    // wave-uniform broadcast read
        acc += (double)Q[(((size_t)n * LQ + p) * HH + h) * EE + e];
    }
    double safe = cnt > 0 ? (double)cnt : 1.0;
    Qg[((size_t)(nh * CC + c)) * EE + e] = acc / safe;
}

// ---------------- K3b: transpose K -> Kt[nh][e][s] ----------------
__global__ __launch_bounds__(256) void k_transpose(const float* __restrict__ Kp,
                                                   float* __restrict__ Kt) {
    int nh = blockIdx.x >> 5;              // 32 s-tiles of 64
    int s0 = (blockIdx.x & 31) * 64;
    int n = nh >> 3, h = nh & 7;
    __shared__ float tile[64][65];
    int t = threadIdx.x;
    int e = t & 63, r0 = t >> 6;
    #pragma unroll
    for (int j = 0; j < 16; j++) {
        int r = r0 * 16 + j;
        tile[r][e] = Kp[(((size_t)n * SS + s0 + r) * HH + h) * EE + e];
    }
    __syncthreads();
    int sl = t & 63, eg = t >> 6;
    #pragma unroll
    for (int j = 0; j < 16; j++) {
        int ee_ = eg * 16 + j;
        Kt[((size_t)nh * EE + ee_) * SS + s0 + sl] = tile[sl][ee_];
    }
}

// ---------------- K4: 4 clusters/block; coalesced Kt; in-register top-k ----------------
__global__ __launch_bounds__(256) void k_rows(const float* __restrict__ Kt,
                                              const float* __restrict__ Vp,
                                              const double* __restrict__ Qg,
                                              int* __restrict__ topi,
                                              float* __restrict__ abk,
                                              float* __restrict__ Vg) {
    int bid = blockIdx.x;
    int nh = bid >> 6, cg = bid & 63;
    int c0 = cg * CG;
    int n = nh >> 3, h = nh & 7;
    int t = threadIdx.x, w = t >> 6, l = t & 63;

    __shared__ double xrow[CG][SS];        // 64KB; overlaid later
    __shared__ double qgl[EE][CG];         // 2KB
    float* wpack = (float*)&xrow[0][0];    // [SS][CG] f32 = 32KB (xrow[0..1])
    float* redv  = (float*)&xrow[2][0];    // 4KB (xrow[2] region, disjoint)

    qgl[t >> 2][t & 3] = Qg[((size_t)(nh * CC + c0 + (t & 3))) * EE + (t >> 2)];
    __syncthreads();

    // ---- phase A: QK scores (f64), coalesced Kt reads ----
    double acc[8][CG];
    #pragma unroll
    for (int r = 0; r < 8; r++)
        #pragma unroll
        for (int c = 0; c < CG; c++) acc[r][c] = 0.0;
    const float* ktb = Kt + ((size_t)nh * EE) * SS + t;
    for (int e = 0; e < EE; e++) {
        double q0 = qgl[e][0], q1 = qgl[e][1], q2 = qgl[e][2], q3 = qgl[e][3];
        const float* kr = ktb + (size_t)e * SS;
        #pragma unroll
        for (int r = 0; r < 8; r++) {
            double kv = (double)kr[r * 256];
            acc[r][0] += q0 * kv; acc[r][1] += q1 * kv;
            acc[r][2] += q2 * kv; acc[r][3] += q3 * kv;
        }
    }
    #pragma unroll
    for (int r = 0; r < 8; r++)
        #pragma unroll
        for (int c = 0; c < CG; c++) xrow[c][t + r * 256] = acc[r][c];
    __syncthreads();

    // ---- phase B: per-wave row (c = w): max, denom, top-32, weights ----
    double v[32];
    #pragma unroll
    for (int k = 0; k < 32; k++) v[k] = xrow[w][l + k * 64];

    double m = v[0];
    #pragma unroll
    for (int k = 1; k < 32; k++) m = v[k] > m ? v[k] : m;
    #pragma unroll
    for (int o = 32; o > 0; o >>= 1) { double z = __shfl_xor(m, o); m = z > m ? z : m; }

    double ds = 0.0;
    #pragma unroll
    for (int k = 0; k < 32; k++) ds += (double)expf(0.125f * (float)(v[k] - m));
    #pragma unroll
    for (int o = 32; o > 0; o >>= 1) ds += __shfl_xor(ds, o);

    unsigned ext = 0;
    double lbv = -1e301; int lbi = 1 << 30;
    #pragma unroll
    for (int k = 0; k < 32; k++)
        if (v[k] > lbv) { lbv = v[k]; lbi = l + k * 64; }
    double topsum = 0.0;
    int rowid = nh * CC + c0 + w;
    for (int kk = 0; kk < TK; kk++) {
        double bv = lbv; int bi = lbi;
        #pragma unroll
        for (int o = 32; o > 0; o >>= 1) {
            double v2 = __shfl_xor(bv, o); int i2 = __shfl_xor(bi, o);
            if (v2 > bv || (v2 == bv && i2 < bi)) { bv = v2; bi = i2; }
        }
        topsum += (double)expf(0.125f * (float)(bv - m));
        if (l == 0) topi[(size_t)rowid * TK + kk] = bi;
        if ((bi & 63) == l) {
            ext |= 1u << (bi >> 6);
            lbv = -1e301; lbi = 1 << 30;
            #pragma unroll
            for (int k = 0; k < 32; k++)
                if (!((ext >> k) & 1) && v[k] > lbv) { lbv = v[k]; lbi = l + k * 64; }
        }
    }
    if (l == 0) abk[rowid] = (float)((ds - topsum) / ds);
    __syncthreads();

    float invd = (float)(1.0 / ds);
    #pragma unroll
    for (int k = 0; k < 32; k++) {
        float wk = ((ext >> k) & 1) ? 0.0f
                 : expf(0.125f * (float)(v[k] - m)) * invd;
        wpack[(l + k * 64) * CG + w] = wk;
    }
    __syncthreads();

    // ---- phase C: Vg = W x V, coalesced V reads, f32 accumulate ----
    {
        int e = l, grp = w;
        float a0 = 0, a1 = 0, a2 = 0, a3 = 0;
        const float* vb = Vp + (((size_t)n * SS) * HH + h) * EE + e;
        const float4* wp4 = (const float4*)wpack;
        for (int s = grp * 512; s < grp * 512 + 512; s++) {
            float4 wv = wp4[s];
            float vv = vb[(size_t)s * HH * EE];
            a0 += wv.x * vv; a1 += wv.y * vv; a2 += wv.z * vv; a3 += wv.w * vv;
        }
        redv[(grp * 4 + 0) * 64 + e] = a0;
        redv[(grp * 4 + 1) * 64 + e] = a1;
        redv[(grp * 4 + 2) * 64 + e] = a2;
        redv[(grp * 4 + 3) * 64 + e] = a3;
        __syncthreads();
        int c = w;
        float s = redv[(0 * 4 + c) * 64 + e] + redv[(1 * 4 + c) * 64 + e]
                + redv[(2 * 4 + c) * 64 + e] + redv[(3 * 4 + c) * 64 + e];
        Vg[((size_t)(nh * CC + c0 + c)) * EE + e] = s;
    }
}

// ---------------- K5: per-query top-32 re-attention + V_bottom ----------------
__global__ __launch_bounds__(256) void k_out(const float* __restrict__ Q,
                                             const float* __restrict__ Kp,
                                             const float* __restrict__ Vp,
                                             const int* __restrict__ clusters,
                                             const int* __restrict__ topi,
                                             const float* __restrict__ abk,
                                             const float* __restrict__ Vg,
                                             float* __restrict__ out) {
    int tid = threadIdx.x, wid = tid >> 6, e = tid & 63;
    int q = blockIdx.x * 4 + wid;            // nh*LQ + l
    int nh = q >> 11, l = q & (LQ - 1);
    int n = nh >> 3, h = nh & 7;
    int c = clusters[q];
    float scale = 1.0f - abk[nh * CC + c];
    const int* ti = topi + (size_t)(nh * CC + c) * TK;
    float qe = Q[(((size_t)n * LQ + l) * HH + h) * EE + e];
    float myv = -INFINITY;
    for (int k = 0; k < TK; k++) {
        int idx = ti[k];
        float kv = Kp[(((size_t)n * SS + idx) * HH + h) * EE + e];
        float v = qe * kv;
        #pragma unroll
        for (int o = 32; o > 0; o >>= 1) v += __shfl_xor(v, o);
        if (e == k) myv = v;
    }
    float mv = myv;
    #pragma unroll
    for (int o = 32; o > 0; o >>= 1) { float v = __shfl_xor(mv, o); mv = v > mv ? v : mv; }
    float p = (e < TK) ? expf(0.125f * (myv - mv)) : 0.0f;
    float ssum = p;
    #pragma unroll
    for (int o = 32; o > 0; o >>= 1) ssum += __shfl_xor(ssum, o);
    float at = p / ssum * scale;
    float acc = 0.0f;
    for (int k = 0; k < TK; k++) {
        float wk = __shfl(at, k, 64);
        int idx = ti[k];
        acc += wk * Vp[(((size_t)n * SS + idx) * HH + h) * EE + e];
    }
    acc += Vg[(size_t)(nh * CC + c) * EE + e];
    out[(((size_t)n * LQ + l) * HH + h) * EE + e] = acc;
}

extern "C" void kernel_launch(void* const* d_in, const int* in_sizes, int n_in,
                              void* d_out, int out_size, void* d_ws, size_t ws_size,
                              hipStream_t stream) {
    const float* Q      = (const float*)d_in[0];
    const float* K      = (const float*)d_in[1];
    const float* V      = (const float*)d_in[2];
    const float* planes = (const float*)d_in[3];
    float* out = (float*)d_out;

    char* ws = (char*)d_ws;
    unsigned int* qmask    = (unsigned int*)(ws);                   // 128KB
    int*          clusters = (int*)(ws + (128 << 10));              // 128KB
    int*          counts   = (int*)(ws + (256 << 10));              // 16KB
    float*        abk      = (float*)(ws + (272 << 10));            // 16KB
    int*          topi     = (int*)(ws + (288 << 10));              // 512KB
    float*        Vg       = (float*)(ws + (800 << 10));            // 1MB
    double*       Qg       = (double*)(ws + (1824 << 10));          // 2MB
    float*        Kt       = (float*)(ws + (4096 << 10));           // 8MB  [4MB,12MB)
    int*          order    = (int*)(ws + (12288 << 10));            // 128KB
    int*          offsets  = (int*)(ws + (12416 << 10));            // 16KB

    k_transpose<<<dim3(NH * 32), dim3(256), 0, stream>>>(K, Kt);
    k_hash<<<dim3(NH * LQ / 256), dim3(256), 0, stream>>>(Q, planes, qmask);
    k_kmeans<<<dim3(NH), dim3(512), 0, stream>>>(qmask, clusters, counts, order, offsets);
    k_qg<<<dim3(NH * 64), dim3(256), 0, stream>>>(Q, order, offsets, counts, Qg);
    k_rows<<<dim3(NH * CC / CG), dim3(256), 0, stream>>>(Kt, V, Qg, topi, abk, Vg);
    k_out<<<dim3(NH * LQ / 4), dim3(256), 0, stream>>>(Q, K, V, clusters, topi, abk, Vg, out);
}

// Round 6
// 444.751 us; speedup vs baseline: 8.5155x; 1.2758x over previous
//
#include <hip/hip_runtime.h>
#include <math.h>
#include <float.h>

// Problem constants (from reference)
#define NB 2
#define LQ 2048
#define HH 8
#define EE 64
#define SS 2048
#define CC 256
#define KM_ITERS 10
#define NBITS 32
#define TK 32
#define NH (NB*HH)
#define CG 4    // clusters per k_rows block

// ---------------- K1: hash bits -> 32-bit mask per (n,h,l) ----------------
__global__ __launch_bounds__(256) void k_hash(const float* __restrict__ Q,
                                              const float* __restrict__ planes,
                                              unsigned int* __restrict__ qmask) {
    int gid = blockIdx.x * 256 + threadIdx.x;      // nh*LQ + l
    int nh = gid >> 11, l = gid & (LQ - 1);
    int n = nh >> 3, h = nh & 7;
    const float* qrow = Q + (((size_t)n * LQ + l) * HH + h) * EE;
    float q[64];
    #pragma unroll
    for (int e = 0; e < 64; e++) q[e] = qrow[e];
    unsigned int m = 0;
    for (int b = 0; b < NBITS; b++) {
        double acc = (double)planes[b * 65 + 64];   // bias
        #pragma unroll
        for (int e = 0; e < 64; e++) acc += (double)q[e] * (double)planes[b * 65 + e];
        if (acc > 0.0) m |= (1u << b);
    }
    qmask[gid] = m;
}

// ---------------- K2a: centroid init ----------------
__global__ __launch_bounds__(256) void k_cinit(const unsigned int* __restrict__ qmask,
                                               unsigned int* __restrict__ cent_g) {
    int nh = blockIdx.x, t = threadIdx.x;
    cent_g[nh * CC + t] = qmask[(size_t)nh * LQ + t * 8];   // init_idx = c*8
}

// ---------------- K2b: assign (data-parallel, 128 blocks) ----------------
// dist packed as (d<<8)|c; integer min == first-min tie-break of jnp.argmin.
__global__ __launch_bounds__(256) void k_assign(const unsigned int* __restrict__ qmask,
                                                const unsigned int* __restrict__ cent_g,
                                                int* __restrict__ asg) {
    int nh = blockIdx.x >> 3;              // 8 blocks per nh
    int p = ((blockIdx.x & 7) << 8) + threadIdx.x;
    int t = threadIdx.x;
    __shared__ __align__(16) unsigned int cent[CC];
    cent[t] = cent_g[nh * CC + t];
    __syncthreads();
    unsigned int m = qmask[(size_t)nh * LQ + p];
    int best = 0x7fffffff;
    const uint4* c4p = (const uint4*)cent;
    #pragma unroll 4
    for (int c4 = 0; c4 < CC / 4; c4++) {
        uint4 cm = c4p[c4];
        int base = c4 << 2;
        int e0 = (__popc(m ^ cm.x) << 8) + base;
        int e1 = (__popc(m ^ cm.y) << 8) + base + 1;
        int e2 = (__popc(m ^ cm.z) << 8) + base + 2;
        int e3 = (__popc(m ^ cm.w) << 8) + base + 3;
        int e01 = e0 < e1 ? e0 : e1;
        int e23 = e2 < e3 ? e2 : e3;
        int e = e01 < e23 ? e01 : e23;
        best = best < e ? best : e;
    }
    asg[(size_t)nh * LQ + p] = best & 255;
}

// ---------------- K2c: update (per-nh counting sort + exact majority) ----------------
__global__ __launch_bounds__(512) void k_update(const unsigned int* __restrict__ qmask,
                                                const int* __restrict__ asg,
                                                unsigned int* __restrict__ cent_g) {
    int nh = blockIdx.x, t = threadIdx.x;
    __shared__ unsigned int sorted[LQ];               // 8KB
    __shared__ int cnts[CC], offs[CC], cursor[CC];
    if (t < CC) cnts[t] = 0;
    int bc[4]; unsigned int mym[4];
    #pragma unroll
    for (int k = 0; k < 4; k++) {
        bc[k] = asg[(size_t)nh * LQ + t + k * 512];
        mym[k] = qmask[(size_t)nh * LQ + t + k * 512];
    }
    __syncthreads();
    #pragma unroll
    for (int k = 0; k < 4; k++) atomicAdd(&cnts[bc[k]], 1);
    __syncthreads();
    if (t < 64) {                                     // single-wave exclusive scan
        int c0 = cnts[4 * t], c1 = cnts[4 * t + 1], c2 = cnts[4 * t + 2], c3 = cnts[4 * t + 3];
        int s1 = c0 + c1, s2 = s1 + c2, tot = s2 + c3;
        int inc = tot;
        #pragma unroll
        for (int o = 1; o < 64; o <<= 1) {
            int v = __shfl_up(inc, o);
            if (t >= o) inc += v;
        }
        int excl = inc - tot;
        offs[4 * t] = excl;          cursor[4 * t] = excl;
        offs[4 * t + 1] = excl + c0; cursor[4 * t + 1] = excl + c0;
        offs[4 * t + 2] = excl + s1; cursor[4 * t + 2] = excl + s1;
        offs[4 * t + 3] = excl + s2; cursor[4 * t + 3] = excl + s2;
    }
    __syncthreads();
    int cl = t >> 1, j = t & 1;
    int cnt_c = cnts[cl], off_c = offs[cl];
    #pragma unroll
    for (int k = 0; k < 4; k++) {
        int pos = atomicAdd(&cursor[bc[k]], 1);
        sorted[pos] = mym[k];
    }
    __syncthreads();
    int bs[32];
    #pragma unroll
    for (int b = 0; b < 32; b++) bs[b] = 0;
    for (int i = j; i < cnt_c; i += 2) {
        unsigned int m = sorted[off_c + i];
        #pragma unroll
        for (int b = 0; b < 32; b++) bs[b] += (m >> b) & 1;
    }
    #pragma unroll
    for (int b = 0; b < 32; b++) bs[b] += __shfl_xor(bs[b], 1);
    if (j == 0 && cnt_c > 0) {
        unsigned int nc = 0;
        #pragma unroll
        for (int b = 0; b < 32; b++) if (2 * bs[b] >= cnt_c) nc |= (1u << b);
        cent_g[nh * CC + cl] = nc;                    // exact majority; keep old if cnt==0
    }
}

// ---------------- K2d: finalize counts/offsets/order from final assignment ----------------
__global__ __launch_bounds__(512) void k_finalize(const int* __restrict__ asg,
                                                  int* __restrict__ counts_out,
                                                  int* __restrict__ order_out,
                                                  int* __restrict__ offsets_out) {
    int nh = blockIdx.x, t = threadIdx.x;
    __shared__ int cnts[CC], offs[CC], cursor[CC];
    if (t < CC) cnts[t] = 0;
    int bc[4];
    #pragma unroll
    for (int k = 0; k < 4; k++) bc[k] = asg[(size_t)nh * LQ + t + k * 512];
    __syncthreads();
    #pragma unroll
    for (int k = 0; k < 4; k++) atomicAdd(&cnts[bc[k]], 1);
    __syncthreads();
    if (t < 64) {
        int c0 = cnts[4 * t], c1 = cnts[4 * t + 1], c2 = cnts[4 * t + 2], c3 = cnts[4 * t + 3];
        int s1 = c0 + c1, s2 = s1 + c2, tot = s2 + c3;
        int inc = tot;
        #pragma unroll
        for (int o = 1; o < 64; o <<= 1) {
            int v = __shfl_up(inc, o);
            if (t >= o) inc += v;
        }
        int excl = inc - tot;
        offs[4 * t] = excl;          cursor[4 * t] = excl;
        offs[4 * t + 1] = excl + c0; cursor[4 * t + 1] = excl + c0;
        offs[4 * t + 2] = excl + s1; cursor[4 * t + 2] = excl + s1;
        offs[4 * t + 3] = excl + s2; cursor[4 * t + 3] = excl + s2;
    }
    __syncthreads();
    if (t < CC) {
        counts_out[nh * CC + t] = cnts[t];
        offsets_out[nh * CC + t] = offs[t];
    }
    #pragma unroll
    for (int k = 0; k < 4; k++) {
        int pos = atomicAdd(&cursor[bc[k]], 1);
        order_out[(size_t)nh * LQ + pos] = t + k * 512;
    }
}

// ---------------- K3: segmented cluster-mean Qg (f64), wave per cluster ----------------
__global__ __launch_bounds__(256) void k_qg(const float* __restrict__ Q,
                                            const int* __restrict__ order,
                                            const int* __restrict__ offsets,
                                            const int* __restrict__ counts,
                                            double* __restrict__ Qg) {
    int nh = blockIdx.x >> 6;              // 64 blocks per nh
    int c = (blockIdx.x & 63) * 4 + (threadIdx.x >> 6);
    int e = threadIdx.x & 63;
    int n = nh >> 3, h = nh & 7;
    int off = offsets[nh * CC + c];
    int cnt = counts[nh * CC + c];
    const int* ord = order + (size_t)nh * LQ + off;
    double acc = 0.0;
    for (int i = 0; i < cnt; i++) {
        int p = ord[i];                    // wave-uniform broadcast read
        acc += (double)Q[(((size_t)n * LQ + p) * HH + h) * EE + e];
    }
    double safe = cnt > 0 ? (double)cnt : 1.0;
    Qg[((size_t)(nh * CC + c)) * EE + e] = acc / safe;
}

// ---------------- K3b: transpose K -> Kt[nh][e][s] ----------------
__global__ __launch_bounds__(256) void k_transpose(const float* __restrict__ Kp,
                                                   float* __restrict__ Kt) {
    int nh = blockIdx.x >> 5;              // 32 s-tiles of 64
    int s0 = (blockIdx.x & 31) * 64;
    int n = nh >> 3, h = nh & 7;
    __shared__ float tile[64][65];
    int t = threadIdx.x;
    int e = t & 63, r0 = t >> 6;
    #pragma unroll
    for (int j = 0; j < 16; j++) {
        int r = r0 * 16 + j;
        tile[r][e] = Kp[(((size_t)n * SS + s0 + r) * HH + h) * EE + e];
    }
    __syncthreads();
    int sl = t & 63, eg = t >> 6;
    #pragma unroll
    for (int j = 0; j < 16; j++) {
        int ee_ = eg * 16 + j;
        Kt[((size_t)nh * EE + ee_) * SS + s0 + sl] = tile[sl][ee_];
    }
}

// ---------------- K4: 4 clusters/block; coalesced Kt; in-register top-k ----------------
__global__ __launch_bounds__(256) void k_rows(const float* __restrict__ Kt,
                                              const float* __restrict__ Vp,
                                              const double* __restrict__ Qg,
                                              int* __restrict__ topi,
                                              float* __restrict__ abk,
                                              float* __restrict__ Vg) {
    int bid = blockIdx.x;
    int nh = bid >> 6, cg = bid & 63;
    int c0 = cg * CG;
    int n = nh >> 3, h = nh & 7;
    int t = threadIdx.x, w = t >> 6, l = t & 63;

    __shared__ double xrow[CG][SS];        // 64KB; overlaid later
    __shared__ double qgl[EE][CG];         // 2KB
    float* wpack = (float*)&xrow[0][0];    // [SS][CG] f32 = 32KB (xrow[0..1])
    float* redv  = (float*)&xrow[2][0];    // 4KB (xrow[2] region, disjoint)

    qgl[t >> 2][t & 3] = Qg[((size_t)(nh * CC + c0 + (t & 3))) * EE + (t >> 2)];
    __syncthreads();

    // ---- phase A: QK scores (f64), coalesced Kt reads ----
    double acc[8][CG];
    #pragma unroll
    for (int r = 0; r < 8; r++)
        #pragma unroll
        for (int c = 0; c < CG; c++) acc[r][c] = 0.0;
    const float* ktb = Kt + ((size_t)nh * EE) * SS + t;
    for (int e = 0; e < EE; e++) {
        double q0 = qgl[e][0], q1 = qgl[e][1], q2 = qgl[e][2], q3 = qgl[e][3];
        const float* kr = ktb + (size_t)e * SS;
        #pragma unroll
        for (int r = 0; r < 8; r++) {
            double kv = (double)kr[r * 256];
            acc[r][0] += q0 * kv; acc[r][1] += q1 * kv;
            acc[r][2] += q2 * kv; acc[r][3] += q3 * kv;
        }
    }
    #pragma unroll
    for (int r = 0; r < 8; r++)
        #pragma unroll
        for (int c = 0; c < CG; c++) xrow[c][t + r * 256] = acc[r][c];
    __syncthreads();

    // ---- phase B: per-wave row (c = w): max, denom, top-32, weights ----
    double v[32];
    #pragma unroll
    for (int k = 0; k < 32; k++) v[k] = xrow[w][l + k * 64];

    double m = v[0];
    #pragma unroll
    for (int k = 1; k < 32; k++) m = v[k] > m ? v[k] : m;
    #pragma unroll
    for (int o = 32; o > 0; o >>= 1) { double z = __shfl_xor(m, o); m = z > m ? z : m; }

    double ds = 0.0;
    #pragma unroll
    for (int k = 0; k < 32; k++) ds += (double)expf(0.125f * (float)(v[k] - m));
    #pragma unroll
    for (int o = 32; o > 0; o >>= 1) ds += __shfl_xor(ds, o);

    unsigned ext = 0;
    double lbv = -1e301; int lbi = 1 << 30;
    #pragma unroll
    for (int k = 0; k < 32; k++)
        if (v[k] > lbv) { lbv = v[k]; lbi = l + k * 64; }
    double topsum = 0.0;
    int rowid = nh * CC + c0 + w;
    for (int kk = 0; kk < TK; kk++) {
        double bv = lbv; int bi = lbi;
        #pragma unroll
        for (int o = 32; o > 0; o >>= 1) {
            double v2 = __shfl_xor(bv, o); int i2 = __shfl_xor(bi, o);
            if (v2 > bv || (v2 == bv && i2 < bi)) { bv = v2; bi = i2; }
        }
        topsum += (double)expf(0.125f * (float)(bv - m));
        if (l == 0) topi[(size_t)rowid * TK + kk] = bi;
        if ((bi & 63) == l) {
            ext |= 1u << (bi >> 6);
            lbv = -1e301; lbi = 1 << 30;
            #pragma unroll
            for (int k = 0; k < 32; k++)
                if (!((ext >> k) & 1) && v[k] > lbv) { lbv = v[k]; lbi = l + k * 64; }
        }
    }
    if (l == 0) abk[rowid] = (float)((ds - topsum) / ds);
    __syncthreads();

    float invd = (float)(1.0 / ds);
    #pragma unroll
    for (int k = 0; k < 32; k++) {
        float wk = ((ext >> k) & 1) ? 0.0f
                 : expf(0.125f * (float)(v[k] - m)) * invd;
        wpack[(l + k * 64) * CG + w] = wk;
    }
    __syncthreads();

    // ---- phase C: Vg = W x V, coalesced V reads, f32 accumulate ----
    {
        int e = l, grp = w;
        float a0 = 0, a1 = 0, a2 = 0, a3 = 0;
        const float* vb = Vp + (((size_t)n * SS) * HH + h) * EE + e;
        const float4* wp4 = (const float4*)wpack;
        for (int s = grp * 512; s < grp * 512 + 512; s++) {
            float4 wv = wp4[s];
            float vv = vb[(size_t)s * HH * EE];
            a0 += wv.x * vv; a1 += wv.y * vv; a2 += wv.z * vv; a3 += wv.w * vv;
        }
        redv[(grp * 4 + 0) * 64 + e] = a0;
        redv[(grp * 4 + 1) * 64 + e] = a1;
        redv[(grp * 4 + 2) * 64 + e] = a2;
        redv[(grp * 4 + 3) * 64 + e] = a3;
        __syncthreads();
        int c = w;
        float s = redv[(0 * 4 + c) * 64 + e] + redv[(1 * 4 + c) * 64 + e]
                + redv[(2 * 4 + c) * 64 + e] + redv[(3 * 4 + c) * 64 + e];
        Vg[((size_t)(nh * CC + c0 + c)) * EE + e] = s;
    }
}

// ---------------- K5: per-query top-32 re-attention + V_bottom ----------------
__global__ __launch_bounds__(256) void k_out(const float* __restrict__ Q,
                                             const float* __restrict__ Kp,
                                             const float* __restrict__ Vp,
                                             const int* __restrict__ clusters,
                                             const int* __restrict__ topi,
                                             const float* __restrict__ abk,
                                             const float* __restrict__ Vg,
                                             float* __restrict__ out) {
    int tid = threadIdx.x, wid = tid >> 6, e = tid & 63;
    int q = blockIdx.x * 4 + wid;            // nh*LQ + l
    int nh = q >> 11, l = q & (LQ - 1);
    int n = nh >> 3, h = nh & 7;
    int c = clusters[q];
    float scale = 1.0f - abk[nh * CC + c];
    const int* ti = topi + (size_t)(nh * CC + c) * TK;
    float qe = Q[(((size_t)n * LQ + l) * HH + h) * EE + e];
    float myv = -INFINITY;
    for (int k = 0; k < TK; k++) {
        int idx = ti[k];
        float kv = Kp[(((size_t)n * SS + idx) * HH + h) * EE + e];
        float v = qe * kv;
        #pragma unroll
        for (int o = 32; o > 0; o >>= 1) v += __shfl_xor(v, o);
        if (e == k) myv = v;
    }
    float mv = myv;
    #pragma unroll
    for (int o = 32; o > 0; o >>= 1) { float v = __shfl_xor(mv, o); mv = v > mv ? v : mv; }
    float p = (e < TK) ? expf(0.125f * (myv - mv)) : 0.0f;
    float ssum = p;
    #pragma unroll
    for (int o = 32; o > 0; o >>= 1) ssum += __shfl_xor(ssum, o);
    float at = p / ssum * scale;
    float acc = 0.0f;
    for (int k = 0; k < TK; k++) {
        float wk = __shfl(at, k, 64);
        int idx = ti[k];
        acc += wk * Vp[(((size_t)n * SS + idx) * HH + h) * EE + e];
    }
    acc += Vg[(size_t)(nh * CC + c) * EE + e];
    out[(((size_t)n * LQ + l) * HH + h) * EE + e] = acc;
}

extern "C" void kernel_launch(void* const* d_in, const int* in_sizes, int n_in,
                              void* d_out, int out_size, void* d_ws, size_t ws_size,
                              hipStream_t stream) {
    const float* Q      = (const float*)d_in[0];
    const float* K      = (const float*)d_in[1];
    const float* V      = (const float*)d_in[2];
    const float* planes = (const float*)d_in[3];
    float* out = (float*)d_out;

    char* ws = (char*)d_ws;
    unsigned int* qmask    = (unsigned int*)(ws);                   // 128KB
    int*          clusters = (int*)(ws + (128 << 10));              // 128KB (= asg)
    int*          counts   = (int*)(ws + (256 << 10));              // 16KB
    float*        abk      = (float*)(ws + (272 << 10));            // 16KB
    int*          topi     = (int*)(ws + (288 << 10));              // 512KB
    float*        Vg       = (float*)(ws + (800 << 10));            // 1MB
    double*       Qg       = (double*)(ws + (1824 << 10));          // 2MB
    float*        Kt       = (float*)(ws + (4096 << 10));           // 8MB  [4MB,12MB)
    int*          order    = (int*)(ws + (12288 << 10));            // 128KB
    int*          offsets  = (int*)(ws + (12416 << 10));            // 16KB
    unsigned int* cent_g   = (unsigned int*)(ws + (12432 << 10));   // 16KB

    k_transpose<<<dim3(NH * 32), dim3(256), 0, stream>>>(K, Kt);
    k_hash<<<dim3(NH * LQ / 256), dim3(256), 0, stream>>>(Q, planes, qmask);
    k_cinit<<<dim3(NH), dim3(256), 0, stream>>>(qmask, cent_g);
    for (int it = 0; it < KM_ITERS; ++it) {
        k_assign<<<dim3(NH * 8), dim3(256), 0, stream>>>(qmask, cent_g, clusters);
        k_update<<<dim3(NH), dim3(512), 0, stream>>>(qmask, clusters, cent_g);
    }
    k_assign<<<dim3(NH * 8), dim3(256), 0, stream>>>(qmask, cent_g, clusters);
    k_finalize<<<dim3(NH), dim3(512), 0, stream>>>(clusters, counts, order, offsets);
    k_qg<<<dim3(NH * 64), dim3(256), 0, stream>>>(Q, order, offsets, counts, Qg);
    k_rows<<<dim3(NH * CC / CG), dim3(256), 0, stream>>>(Kt, V, Qg, topi, abk, Vg);
    k_out<<<dim3(NH * LQ / 4), dim3(256), 0, stream>>>(Q, K, V, clusters, topi, abk, Vg, out);
}